// Round 12
// baseline (213.960 us; speedup 1.0000x reference)
//
#include <hip/hip_runtime.h>

#define WID 256
#define EPS_GN 1e-5f

typedef __bf16 v8bf __attribute__((ext_vector_type(8)));
typedef __bf16 v2bf __attribute__((ext_vector_type(2)));
typedef float  v4f  __attribute__((ext_vector_type(4)));
typedef float  v2f  __attribute__((ext_vector_type(2)));

__device__ inline unsigned short f2b(float f) {
    unsigned int u = __builtin_bit_cast(unsigned int, f);
    unsigned int r = (u + 0x7fffu + ((u >> 16) & 1u)) >> 16;
    return (unsigned short)r;
}
__device__ inline float lo16(unsigned int u) { return __builtin_bit_cast(float, u << 16); }
__device__ inline float hi16(unsigned int u) { return __builtin_bit_cast(float, u & 0xffff0000u); }
__device__ inline v2f unpk(unsigned int u) {
    v2f r; r.x = lo16(u); r.y = hi16(u); return r;
}

// ---- real packed-f32 VOP3P (clang scalarizes v2f arithmetic; asm forces pk ops) ----
__device__ inline v2f pk_add(v2f a, v2f b) {
    v2f d; asm("v_pk_add_f32 %0, %1, %2" : "=v"(d) : "v"(a), "v"(b)); return d;
}
__device__ inline v2f pk_mul(v2f a, v2f b) {
    v2f d; asm("v_pk_mul_f32 %0, %1, %2" : "=v"(d) : "v"(a), "v"(b)); return d;
}
__device__ inline v2f pk_fma(v2f a, v2f b, v2f c) {
    v2f d; asm("v_pk_fma_f32 %0, %1, %2, %3" : "=v"(d) : "v"(a), "v"(b), "v"(c)); return d;
}

#if __has_builtin(__builtin_amdgcn_cvt_pk_bf16_f32)
__device__ inline unsigned int pkbf(float a, float b) {
    v2bf r = __builtin_amdgcn_cvt_pk_bf16_f32(a, b);
    return __builtin_bit_cast(unsigned int, r);
}
#else
__device__ inline unsigned int pkbf(float a, float b) {
    return (unsigned int)f2b(a) | ((unsigned int)f2b(b) << 16);
}
#endif

#if __has_builtin(__builtin_amdgcn_fdot2_f32_bf16)
__device__ inline float pairsum(unsigned int u, float s) {
    v2bf p = __builtin_bit_cast(v2bf, u);
    v2bf ones = __builtin_bit_cast(v2bf, 0x3f803f80u);
    return __builtin_amdgcn_fdot2_f32_bf16(p, ones, s, false);
}
#else
__device__ inline float pairsum(unsigned int u, float s) {
    return s + lo16(u) + hi16(u);
}
#endif

// ===== cast weights (vectorized, R9-verified) + pad tail + histogram =====
// NOTE (R8 lesson): NO __threadfence() — device-scope fence on gfx950 = L2 flush.
// NOTE (R10 lesson): do NOT pre-swizzle weights — moves the gather to the producer.
__global__ void cast_k(const float* __restrict__ Wsrc, const float* __restrict__ Wtgt,
                       const float* __restrict__ Wp, const float* __restrict__ Wg,
                       const float* __restrict__ Wv, const float* __restrict__ emb,
                       const int* __restrict__ eidx,
                       unsigned short* __restrict__ Wsb, unsigned short* __restrict__ Wtb,
                       unsigned short* __restrict__ Wpb, unsigned short* __restrict__ Wgb,
                       unsigned short* __restrict__ Wvb, unsigned short* __restrict__ embWgT,
                       int* __restrict__ cnt, int* __restrict__ ssrc,
                       int* __restrict__ stgt, int* __restrict__ sattr,
                       int N, int BOND, int E, int NT32) {
    int i = blockIdx.x * 256 + threadIdx.x;  // 640*256 = 163840 threads (2.5 blocks/CU)
    int gsz = gridDim.x * 256;
    for (int j = E + i; j < NT32; j += gsz) { ssrc[j] = 0; stgt[j] = 0; sattr[j] = 0; }
    for (int j = i; j < E; j += gsz) atomicAdd(&cnt[eidx[E + j]], 1);
    {
        const float2* s2 = (const float2*)Wsrc;
        const float2* t2 = (const float2*)Wtgt;
        const float2* p2 = (const float2*)Wp;
        unsigned int* so = (unsigned int*)Wsb;
        unsigned int* to = (unsigned int*)Wtb;
        unsigned int* po = (unsigned int*)Wpb;
        for (int j = i; j < 32768; j += gsz) {
            float2 a = s2[j], b = t2[j], c = p2[j];
            so[j] = pkbf(a.x, a.y); to[j] = pkbf(b.x, b.y); po[j] = pkbf(c.x, c.y);
        }
    }
    {
        const float2* g2 = (const float2*)Wg;
        const float2* v2p = (const float2*)Wv;
        unsigned int* go = (unsigned int*)Wgb;
        unsigned int* vo = (unsigned int*)Wvb;
        for (int j = i; j < 4096; j += gsz) {
            float2 a = g2[j], b = v2p[j];
            go[j] = pkbf(a.x, a.y); vo[j] = pkbf(b.x, b.y);
        }
    }
    for (int j = i; j < 8192; j += gsz) {
        int jr = j >> 5, k = j & 31;
        int kk = k ? k : 32;      // slot 0 <- bond 32
        float sacc = 0.f;
        if (kk < BOND) {
            int h = jr >> 5, f = jr & 31;
            const float4* er = (const float4*)(emb + (size_t)kk * WID + h * 32);
            const float4* wr = (const float4*)(Wg + h * 1024 + f * 32);
#pragma unroll
            for (int d = 0; d < 8; d++) {
                float4 e4 = er[d], w4 = wr[d];
                sacc += e4.x * w4.x + e4.y * w4.y + e4.z * w4.z + e4.w * w4.w;
            }
        }
        embWgT[jr * 32 + k] = f2b(sacc);
    }
}

// ===== exclusive scan: wave-shfl based, 4 barriers (R11-verified) =====
__global__ void scan_k(const int* __restrict__ cnt, int* __restrict__ cur, int N) {
    __shared__ int buf[10240];   // N <= 10240
    __shared__ int wsum[16];
    int t = threadIdx.x;         // 1024 threads = 16 waves
    int C = (N + 1023) >> 10;
    int M = C << 10;
    for (int i = t; i < M; i += 1024) buf[i] = (i < N) ? cnt[i] : 0;
    __syncthreads();
    int base0 = t * C;
    int s = 0;
    for (int i = 0; i < C; i++) s += buf[base0 + i];
    // inclusive 64-lane wave scan of per-thread sums (no barriers)
    int lane = t & 63, wv = t >> 6;
    int v = s;
#pragma unroll
    for (int d = 1; d < 64; d <<= 1) {
        int u = __shfl_up(v, d);
        if (lane >= d) v += u;
    }
    if (lane == 63) wsum[wv] = v;
    __syncthreads();
    if (wv == 0 && lane < 16) {
        int x = wsum[lane];
#pragma unroll
        for (int d = 1; d < 16; d <<= 1) {
            int u = __shfl_up(x, d, 16);
            if (lane >= d) x += u;
        }
        wsum[lane] = x;   // inclusive wave-sum scan
    }
    __syncthreads();
    int waveoff = (wv == 0) ? 0 : wsum[wv - 1];
    int base = waveoff + (v - s);   // global exclusive prefix for this thread's chunk
    for (int i = 0; i < C; i++) {
        int val = buf[base0 + i];
        buf[base0 + i] = base;
        base += val;
    }
    __syncthreads();
    for (int i = t; i < N; i += 1024) cur[i] = buf[i];
}

// ===== proj (R2/R9-verified 32-node MFMA tiles) + aux blocks run the SCATTER =====
__global__ __launch_bounds__(256, 2)
void prepproj_k(const float* __restrict__ x, const unsigned short* __restrict__ Wsb,
                const unsigned short* __restrict__ Wtb, const int* __restrict__ eidx,
                const int* __restrict__ eattr, int* __restrict__ cur,
                int* __restrict__ ssrc, int* __restrict__ stgt, int* __restrict__ sattr,
                unsigned short* __restrict__ xsb, unsigned short* __restrict__ xtb,
                int N, int E, int PB, int AUX) {
    __shared__ unsigned short ab[32 * 264];
    int t = threadIdx.x, b = blockIdx.x;

    if (b >= PB) {
        // scatter: write edge payload directly in sorted position (overlaps MFMA blocks)
        int atid = (b - PB) * 256 + t, asz = AUX * 256;
        for (int i = atid; i < E; i += asz) {
            int tg = eidx[E + i];
            int p = atomicAdd(&cur[tg], 1);
            ssrc[p] = eidx[i];
            stgt[p] = tg;
            const int* ap = eattr + (size_t)i * 3;
            sattr[p] = (ap[0] & 63) | ((ap[1] & 63) << 6) | ((ap[2] & 63) << 12);
        }
        return;
    }

    int n0 = b * 32;
#pragma unroll
    for (int ch = 0; ch < 8; ch++) {
        int flat = ch * 1024 + t * 4;
        int row = flat >> 8, col = flat & 255;
        int n = n0 + row;
        float4 v = (n < N) ? *(const float4*)&x[(size_t)n * WID + col]
                           : make_float4(0.f, 0.f, 0.f, 0.f);
        *(uint2*)&ab[row * 264 + col] = make_uint2(pkbf(v.x, v.y), pkbf(v.z, v.w));
    }
    __syncthreads();
    int w = t >> 6, lane = t & 63, m = lane & 15, kg = lane >> 4;
#pragma unroll
    for (int pass = 0; pass < 2; pass++) {
        const unsigned short* Wb = pass ? Wtb : Wsb;
        unsigned short* outp = pass ? xtb : xsb;
        v4f acc[2][4];
#pragma unroll
        for (int mt = 0; mt < 2; mt++)
#pragma unroll
            for (int nt = 0; nt < 4; nt++) acc[mt][nt] = (v4f){0.f, 0.f, 0.f, 0.f};
#pragma unroll
        for (int kt = 0; kt < 8; kt++) {
            int k0 = kt * 32 + kg * 8;
            v8bf a0 = *(const v8bf*)&ab[m * 264 + k0];
            v8bf a1 = *(const v8bf*)&ab[(16 + m) * 264 + k0];
#pragma unroll
            for (int nt = 0; nt < 4; nt++) {
                int j = w * 64 + nt * 16 + m;
                v8bf bfr = *(const v8bf*)&Wb[j * 256 + k0];
                // swapped: M-dim = weight rows j, N-dim = nodes
                acc[0][nt] = __builtin_amdgcn_mfma_f32_16x16x32_bf16(bfr, a0, acc[0][nt], 0, 0, 0);
                acc[1][nt] = __builtin_amdgcn_mfma_f32_16x16x32_bf16(bfr, a1, acc[1][nt], 0, 0, 0);
            }
        }
        // lane m = node within 16; regs r = 4 consecutive output cols -> 8B stores
#pragma unroll
        for (int mt = 0; mt < 2; mt++) {
            int n = n0 + mt * 16 + m;
            if (n < N) {
#pragma unroll
                for (int nt = 0; nt < 4; nt++) {
                    int j0 = w * 64 + nt * 16 + kg * 4;
                    *(uint2*)&outp[(size_t)n * WID + j0] =
                        make_uint2(pkbf(acc[mt][nt][0], acc[mt][nt][1]),
                                   pkbf(acc[mt][nt][2], acc[mt][nt][3]));
                }
            }
        }
    }
}

// ============ fused edge pipeline: R4/R6/R7/R9/R11-verified byte-identical ============
__global__ __launch_bounds__(256, 8)
void edge_k(const unsigned short* __restrict__ xsb, const unsigned short* __restrict__ xtb,
            const int* __restrict__ ssrc, const int* __restrict__ stgt,
            const int* __restrict__ sattr, const unsigned short* __restrict__ Wgb,
            const unsigned short* __restrict__ Wvb, const unsigned short* __restrict__ embWgT,
            float* __restrict__ aggact, int E, int NT, int PER) {
    __shared__ unsigned short xxb[8704];      // xn (32 x 264) -> act_t (256 x stride 34)
    __shared__ unsigned short Mld[32 * 40];   // M rows: 32 cols used (bond32 -> slot 0)
    __shared__ int src_s[32], tgt_s[32];
    __shared__ int segmask_s;

    // XCD-aware swizzle
    int tile = (blockIdx.x & 7) * PER + (blockIdx.x >> 3);
    if (tile >= NT) return;
    int t = threadIdx.x;
    int e0 = tile * 32;
    int ne = min(32, E - e0);

    // init: coalesced sorted-payload loads, M rows, segment flush bitmask
    {
        int tgtv = -1;
        if (t < 32) {
            int e = e0 + t;
            src_s[t] = ssrc[e];
            int tg = stgt[e];
            tgt_s[t] = tg;
            int pa = sattr[e];
            uint4* Mr = (uint4*)&Mld[t * 40];
#pragma unroll
            for (int q = 0; q < 4; q++) Mr[q] = make_uint4(0u, 0u, 0u, 0u);
            int a0 = pa & 63, a1 = (pa >> 6) & 63, a2 = (pa >> 12) & 63;
            int c = (a0 != 0) + (a1 != 0) + (a2 != 0);
            float inv = (c > 0) ? 1.f / (float)c : 0.f;
            float wa = inv * (float)(1 + (a1 == a0) + (a2 == a0));
            float wb = inv * (float)(1 + (a2 == a1));
            if (a0) Mld[t * 40 + (a0 & 31)] = f2b(wa);
            if (a1 && a1 != a0) Mld[t * 40 + (a1 & 31)] = f2b(wb);
            if (a2 && a2 != a0 && a2 != a1) Mld[t * 40 + (a2 & 31)] = f2b(inv);
            tgtv = (t < ne) ? tg : -1;
        }
        if (t < 64) {
            int nxt = __shfl_down(tgtv, 1);
            bool flag = (t < ne) && ((t == ne - 1) || (nxt != tgtv));
            unsigned long long bal = __ballot(flag);
            if (t == 0) segmask_s = (int)(unsigned int)bal;
        }
    }
    __syncthreads();

    // P1: gather + GN stats (4-lane butterfly) -> bf16 xn; packed-f32 via asm
    {
        int e = t >> 3, c = t & 7;
        int sn = src_s[e], g = tgt_s[e];
        const uint4* ps = (const uint4*)(xsb + (size_t)sn * WID);
        const uint4* pt = (const uint4*)(xtb + (size_t)g * WID);
        uint4 us[4], ut[4];
#pragma unroll
        for (int i = 0; i < 4; i++) { us[i] = ps[c + 8 * i]; ut[i] = pt[c + 8 * i]; }
        v2f v2[4][4];
        float sum[4], sq[4];
#pragma unroll
        for (int i = 0; i < 4; i++) {
            const unsigned int* au = (const unsigned int*)&us[i];
            const unsigned int* bu = (const unsigned int*)&ut[i];
            v2f s2 = (v2f){0.f, 0.f}, q2 = (v2f){0.f, 0.f};
#pragma unroll
            for (int q = 0; q < 4; q++) {
                v2f a = pk_add(unpk(au[q]), unpk(bu[q]));
                v2[i][q] = a;
                s2 = pk_add(s2, a);
                q2 = pk_fma(a, a, q2);
            }
            sum[i] = s2.x + s2.y;
            sq[i]  = q2.x + q2.y;
        }
#pragma unroll
        for (int mask = 1; mask <= 2; mask <<= 1)
#pragma unroll
            for (int i = 0; i < 4; i++) {
                sum[i] += __shfl_xor(sum[i], mask);
                sq[i]  += __shfl_xor(sq[i], mask);
            }
#pragma unroll
        for (int i = 0; i < 4; i++) {
            float mu = sum[i] * (1.f / 32.f);
            float var = sq[i] * (1.f / 32.f) - mu * mu;
            float rs = rsqrtf(var + EPS_GN);
            float nmr = -mu * rs;
            v2f rs2 = (v2f){rs, rs}, nm2 = (v2f){nmr, nmr};
            unsigned int pk[4];
#pragma unroll
            for (int q = 0; q < 4; q++) {
                v2f r = pk_fma(v2[i][q], rs2, nm2);
                pk[q] = pkbf(r.x, r.y);
            }
            *(uint4*)&xxb[e * 264 + (c + 8 * i) * 8] = make_uint4(pk[0], pk[1], pk[2], pk[3]);
        }
    }
    __syncthreads();

    // P5: gate/val MFMA (single K=32 bias MFMA) -> act stored TRANSPOSED (stride 34)
    {
        int w = t >> 6, lane = t & 63, m = lane & 15, kg = lane >> 4;
        v8bf axn[2][2], aM[2];
#pragma unroll
        for (int mt = 0; mt < 2; mt++) {
            int row = mt * 16 + m;
            axn[0][mt] = *(const v8bf*)&xxb[row * 264 + (w * 2 + 0) * 32 + kg * 8];
            axn[1][mt] = *(const v8bf*)&xxb[row * 264 + (w * 2 + 1) * 32 + kg * 8];
            aM[mt] = *(const v8bf*)&Mld[row * 40 + kg * 8];
        }
        __syncthreads();  // xn fully consumed before act_t overwrites xxb
        v4f z = {0.f, 0.f, 0.f, 0.f};
#pragma unroll
        for (int hh = 0; hh < 2; hh++) {
            int h = w * 2 + hh;
#pragma unroll
            for (int nt = 0; nt < 2; nt++) {
                int fj = nt * 16 + m;
                int j = h * 32 + fj;
                v8bf bWg = *(const v8bf*)&Wgb[h * 1024 + fj * 32 + kg * 8];
                v8bf bWv = *(const v8bf*)&Wvb[h * 1024 + fj * 32 + kg * 8];
                v8bf bE  = *(const v8bf*)&embWgT[j * 32 + kg * 8];
#pragma unroll
                for (int mt = 0; mt < 2; mt++) {
                    v4f cgm = __builtin_amdgcn_mfma_f32_16x16x32_bf16(axn[hh][mt], bWg, z, 0, 0, 0);
                    cgm = __builtin_amdgcn_mfma_f32_16x16x32_bf16(aM[mt], bE, cgm, 0, 0, 0);
                    v4f cv = __builtin_amdgcn_mfma_f32_16x16x32_bf16(axn[hh][mt], bWv, z, 0, 0, 0);
                    v2f g0 = (v2f){fmaxf(cgm[0], 0.f), fmaxf(cgm[1], 0.f)};
                    v2f g1 = (v2f){fmaxf(cgm[2], 0.f), fmaxf(cgm[3], 0.f)};
                    g0 = pk_mul(g0, (v2f){cv[0], cv[1]});
                    g1 = pk_mul(g1, (v2f){cv[2], cv[3]});
                    int e0i = mt * 16 + kg * 4;  // even -> uint-aligned
                    *(unsigned int*)&xxb[j * 34 + e0i]     = pkbf(g0.x, g0.y);
                    *(unsigned int*)&xxb[j * 34 + e0i + 2] = pkbf(g1.x, g1.y);
                }
            }
        }
    }
    __syncthreads();

    // P6: segmented column reduce; packed pair-sums, scalar bit-test flushes
    {
        unsigned int mask = (unsigned int)__builtin_amdgcn_readfirstlane(segmask_s);
        float sum = 0.f;
#pragma unroll
        for (int i = 0; i < 16; i++) {
            unsigned int r = *(const unsigned int*)&xxb[t * 34 + 2 * i];
            if (!((mask >> (2 * i)) & 1)) {
                sum = pairsum(r, sum);
                if ((mask >> (2 * i + 1)) & 1) {
                    int tg = __builtin_amdgcn_readfirstlane(tgt_s[2 * i + 1]);
                    atomicAdd(&aggact[(size_t)tg * WID + t], sum);
                    sum = 0.f;
                }
            } else {
                sum += lo16(r);
                int tg = __builtin_amdgcn_readfirstlane(tgt_s[2 * i]);
                atomicAdd(&aggact[(size_t)tg * WID + t], sum);
                sum = hi16(r);
                if ((mask >> (2 * i + 1)) & 1) {
                    int tg2 = __builtin_amdgcn_readfirstlane(tgt_s[2 * i + 1]);
                    atomicAdd(&aggact[(size_t)tg2 * WID + t], sum);
                    sum = 0.f;
                }
            }
        }
    }
}

// ============ post (R2/R9-verified 32-node tiles, launch_bounds(256,2)) ============
__global__ __launch_bounds__(256, 2)
void post_k(const float* __restrict__ aggact, const unsigned short* __restrict__ Wpb,
            const float* __restrict__ deg, const float* __restrict__ dp,
            float* __restrict__ out, int N) {
    __shared__ unsigned short ab[32 * 264];
    __shared__ float degl[32];
    int t = threadIdx.x;
    int n0 = blockIdx.x * 32;
#pragma unroll
    for (int ch = 0; ch < 8; ch++) {
        int flat = ch * 1024 + t * 4;
        int row = flat >> 8, col = flat & 255;
        int n = n0 + row;
        float4 v = (n < N) ? *(const float4*)&aggact[(size_t)n * WID + col]
                           : make_float4(0.f, 0.f, 0.f, 0.f);
        *(uint2*)&ab[row * 264 + col] = make_uint2(pkbf(v.x, v.y), pkbf(v.z, v.w));
    }
    if (t < 32) {
        int n = n0 + t;
        degl[t] = (n < N) ? log2f(deg[n]) : 0.f;
    }
    __syncthreads();
    int w = t >> 6, lane = t & 63, m = lane & 15, kg = lane >> 4;
    v4f acc[2][4];
#pragma unroll
    for (int mt = 0; mt < 2; mt++)
#pragma unroll
        for (int nt = 0; nt < 4; nt++) acc[mt][nt] = (v4f){0.f, 0.f, 0.f, 0.f};
#pragma unroll
    for (int kt = 0; kt < 8; kt++) {
        int k0 = kt * 32 + kg * 8;
        v8bf a0 = *(const v8bf*)&ab[m * 264 + k0];
        v8bf a1 = *(const v8bf*)&ab[(16 + m) * 264 + k0];
#pragma unroll
        for (int nt = 0; nt < 4; nt++) {
            int j = w * 64 + nt * 16 + m;
            v8bf b = *(const v8bf*)&Wpb[j * 256 + k0];
            // swapped: M-dim = Wp rows j, N-dim = nodes
            acc[0][nt] = __builtin_amdgcn_mfma_f32_16x16x32_bf16(b, a0, acc[0][nt], 0, 0, 0);
            acc[1][nt] = __builtin_amdgcn_mfma_f32_16x16x32_bf16(b, a1, acc[1][nt], 0, 0, 0);
        }
    }
#pragma unroll
    for (int mt = 0; mt < 2; mt++) {
        int n = n0 + mt * 16 + m;
        if (n < N) {
            float ld = degl[mt * 16 + m];
#pragma unroll
            for (int nt = 0; nt < 4; nt++) {
                int j0 = w * 64 + nt * 16 + kg * 4;
                float4 dv = *(const float4*)&dp[j0];
                float4 o;
                o.x = exp2f(dv.x * ld) * acc[mt][nt][0];
                o.y = exp2f(dv.y * ld) * acc[mt][nt][1];
                o.z = exp2f(dv.z * ld) * acc[mt][nt][2];
                o.w = exp2f(dv.w * ld) * acc[mt][nt][3];
                *(float4*)&out[(size_t)n * WID + j0] = o;
            }
        }
    }
}

extern "C" void kernel_launch(void* const* d_in, const int* in_sizes, int n_in,
                              void* d_out, int out_size, void* d_ws, size_t ws_size,
                              hipStream_t stream) {
    const float* x    = (const float*)d_in[0];
    const float* deg  = (const float*)d_in[1];
    const int*   eidx = (const int*)d_in[2];
    const int*   eatt = (const int*)d_in[3];
    const float* Wsrc = (const float*)d_in[4];
    const float* Wtgt = (const float*)d_in[5];
    const float* emb  = (const float*)d_in[6];
    const float* Wg   = (const float*)d_in[7];
    const float* Wv   = (const float*)d_in[8];
    const float* Wp   = (const float*)d_in[9];
    const float* dp   = (const float*)d_in[10];
    int N = in_sizes[0] / WID;
    int E = in_sizes[2] / 2;
    int BOND = in_sizes[6] / WID;

    int NT = (E + 31) / 32;
    int NT32 = NT * 32;

    float* ws     = (float*)d_ws;
    float* aggact = ws;
    int*   cnt    = (int*)(aggact + (size_t)N * WID);
    int*   cur    = cnt + N;
    int*   ssrc   = cur + N;
    int*   stgt   = ssrc + NT32;
    int*   sattr  = stgt + NT32;
    unsigned short* xsb = (unsigned short*)(sattr + NT32);
    unsigned short* xtb = xsb + (size_t)N * WID;
    unsigned short* Wsb = xtb + (size_t)N * WID;
    unsigned short* Wtb = Wsb + 65536;
    unsigned short* Wpb = Wtb + 65536;
    unsigned short* Wgb = Wpb + 65536;
    unsigned short* Wvb = Wgb + 8192;
    unsigned short* embWgT = Wvb + 8192;

    int PB = (N + 31) / 32;
    int AUX = 128;
    int PER = (NT + 7) / 8;

    // ONE memset covers aggact (N*WID floats) + cnt (N ints) — adjacent in ws
    hipMemsetAsync(aggact, 0, (size_t)N * WID * sizeof(float) + (size_t)N * sizeof(int),
                   stream);

    cast_k<<<640, 256, 0, stream>>>(Wsrc, Wtgt, Wp, Wg, Wv, emb, eidx,
                                    Wsb, Wtb, Wpb, Wgb, Wvb, embWgT,
                                    cnt, ssrc, stgt, sattr, N, BOND, E, NT32);
    scan_k<<<1, 1024, 0, stream>>>(cnt, cur, N);
    prepproj_k<<<PB + AUX, 256, 0, stream>>>(x, Wsb, Wtb, eidx, eatt, cur,
                                             ssrc, stgt, sattr, xsb, xtb,
                                             N, E, PB, AUX);
    edge_k<<<PER * 8, 256, 0, stream>>>(xsb, xtb, ssrc, stgt, sattr, Wgb, Wvb, embWgT,
                                        aggact, E, NT, PER);
    post_k<<<PB, 256, 0, stream>>>(aggact, Wpb, deg, dp, (float*)d_out, N);
}

// Round 13
// 211.135 us; speedup vs baseline: 1.0134x; 1.0134x over previous
//
#include <hip/hip_runtime.h>

#define WID 256
#define EPS_GN 1e-5f

typedef __bf16 v8bf __attribute__((ext_vector_type(8)));
typedef __bf16 v2bf __attribute__((ext_vector_type(2)));
typedef float  v4f  __attribute__((ext_vector_type(4)));
typedef float  v2f  __attribute__((ext_vector_type(2)));

__device__ inline unsigned short f2b(float f) {
    unsigned int u = __builtin_bit_cast(unsigned int, f);
    unsigned int r = (u + 0x7fffu + ((u >> 16) & 1u)) >> 16;
    return (unsigned short)r;
}
__device__ inline float lo16(unsigned int u) { return __builtin_bit_cast(float, u << 16); }
__device__ inline float hi16(unsigned int u) { return __builtin_bit_cast(float, u & 0xffff0000u); }
__device__ inline v2f unpk(unsigned int u) {
    v2f r; r.x = lo16(u); r.y = hi16(u); return r;
}

// ---- real packed-f32 VOP3P (clang scalarizes v2f arithmetic; asm forces pk ops) ----
__device__ inline v2f pk_add(v2f a, v2f b) {
    v2f d; asm("v_pk_add_f32 %0, %1, %2" : "=v"(d) : "v"(a), "v"(b)); return d;
}
__device__ inline v2f pk_mul(v2f a, v2f b) {
    v2f d; asm("v_pk_mul_f32 %0, %1, %2" : "=v"(d) : "v"(a), "v"(b)); return d;
}
__device__ inline v2f pk_fma(v2f a, v2f b, v2f c) {
    v2f d; asm("v_pk_fma_f32 %0, %1, %2, %3" : "=v"(d) : "v"(a), "v"(b), "v"(c)); return d;
}

#if __has_builtin(__builtin_amdgcn_cvt_pk_bf16_f32)
__device__ inline unsigned int pkbf(float a, float b) {
    v2bf r = __builtin_amdgcn_cvt_pk_bf16_f32(a, b);
    return __builtin_bit_cast(unsigned int, r);
}
#else
__device__ inline unsigned int pkbf(float a, float b) {
    return (unsigned int)f2b(a) | ((unsigned int)f2b(b) << 16);
}
#endif

#if __has_builtin(__builtin_amdgcn_fdot2_f32_bf16)
__device__ inline float pairsum(unsigned int u, float s) {
    v2bf p = __builtin_bit_cast(v2bf, u);
    v2bf ones = __builtin_bit_cast(v2bf, 0x3f803f80u);
    return __builtin_amdgcn_fdot2_f32_bf16(p, ones, s, false);
}
#else
__device__ inline float pairsum(unsigned int u, float s) {
    return s + lo16(u) + hi16(u);
}
#endif

// ===== cast (Wsrc/Wtgt only) + pad tail + histogram — shortened critical path =====
// Wpb/Wgb/Wvb/embWgT casting moved to prepproj's aux blocks (only edge/post need them).
// NOTE (R8 lesson): NO __threadfence() — device-scope fence on gfx950 = L2 flush.
__global__ void cast_k(const float* __restrict__ Wsrc, const float* __restrict__ Wtgt,
                       const int* __restrict__ eidx,
                       unsigned short* __restrict__ Wsb, unsigned short* __restrict__ Wtb,
                       int* __restrict__ cnt, int* __restrict__ ssrc,
                       int* __restrict__ stgt, int* __restrict__ sattr,
                       int N, int E, int NT32) {
    int i = blockIdx.x * 256 + threadIdx.x;  // 320*256 = 81920 threads
    int gsz = gridDim.x * 256;
    for (int j = E + i; j < NT32; j += gsz) { ssrc[j] = 0; stgt[j] = 0; sattr[j] = 0; }
    for (int j = i; j < E; j += gsz) atomicAdd(&cnt[eidx[E + j]], 1);
    {
        const float2* s2 = (const float2*)Wsrc;
        const float2* t2 = (const float2*)Wtgt;
        unsigned int* so = (unsigned int*)Wsb;
        unsigned int* to = (unsigned int*)Wtb;
        for (int j = i; j < 32768; j += gsz) {
            float2 a = s2[j], b = t2[j];
            so[j] = pkbf(a.x, a.y); to[j] = pkbf(b.x, b.y);
        }
    }
}

// ===== exclusive scan: wave-shfl based (R11-verified) =====
__global__ void scan_k(const int* __restrict__ cnt, int* __restrict__ cur, int N) {
    __shared__ int buf[10240];   // N <= 10240
    __shared__ int wsum[16];
    int t = threadIdx.x;         // 1024 threads = 16 waves
    int C = (N + 1023) >> 10;
    int M = C << 10;
    for (int i = t; i < M; i += 1024) buf[i] = (i < N) ? cnt[i] : 0;
    __syncthreads();
    int base0 = t * C;
    int s = 0;
    for (int i = 0; i < C; i++) s += buf[base0 + i];
    int lane = t & 63, wv = t >> 6;
    int v = s;
#pragma unroll
    for (int d = 1; d < 64; d <<= 1) {
        int u = __shfl_up(v, d);
        if (lane >= d) v += u;
    }
    if (lane == 63) wsum[wv] = v;
    __syncthreads();
    if (wv == 0 && lane < 16) {
        int x = wsum[lane];
#pragma unroll
        for (int d = 1; d < 16; d <<= 1) {
            int u = __shfl_up(x, d, 16);
            if (lane >= d) x += u;
        }
        wsum[lane] = x;
    }
    __syncthreads();
    int waveoff = (wv == 0) ? 0 : wsum[wv - 1];
    int base = waveoff + (v - s);
    for (int i = 0; i < C; i++) {
        int val = buf[base0 + i];
        buf[base0 + i] = base;
        base += val;
    }
    __syncthreads();
    for (int i = t; i < N; i += 1024) cur[i] = buf[i];
}

// ===== proj: FUSED two-pass MFMA (shared A-fragments, interleaved chains);
//       aux blocks run the SCATTER + remaining weight casts (overlapped) =====
__global__ __launch_bounds__(256, 2)
void prepproj_k(const float* __restrict__ x, const unsigned short* __restrict__ Wsb,
                const unsigned short* __restrict__ Wtb, const int* __restrict__ eidx,
                const int* __restrict__ eattr, int* __restrict__ cur,
                int* __restrict__ ssrc, int* __restrict__ stgt, int* __restrict__ sattr,
                unsigned short* __restrict__ xsb, unsigned short* __restrict__ xtb,
                const float* __restrict__ Wp, const float* __restrict__ Wg,
                const float* __restrict__ Wv, const float* __restrict__ emb,
                unsigned short* __restrict__ Wpb, unsigned short* __restrict__ Wgb,
                unsigned short* __restrict__ Wvb, unsigned short* __restrict__ embWgT,
                int N, int E, int PB, int AUX, int BOND) {
    __shared__ unsigned short ab[32 * 264];
    int t = threadIdx.x, b = blockIdx.x;

    if (b >= PB) {
        int atid = (b - PB) * 256 + t, asz = AUX * 256;
        // scatter: write edge payload directly in sorted position
        for (int i = atid; i < E; i += asz) {
            int tg = eidx[E + i];
            int p = atomicAdd(&cur[tg], 1);
            ssrc[p] = eidx[i];
            stgt[p] = tg;
            const int* ap = eattr + (size_t)i * 3;
            sattr[p] = (ap[0] & 63) | ((ap[1] & 63) << 6) | ((ap[2] & 63) << 12);
        }
        // cast Wp -> Wpb (needed by post_k, launched later)
        {
            const float2* p2 = (const float2*)Wp;
            unsigned int* po = (unsigned int*)Wpb;
            for (int j = atid; j < 32768; j += asz) {
                float2 c = p2[j];
                po[j] = pkbf(c.x, c.y);
            }
        }
        // cast Wg/Wv -> Wgb/Wvb (needed by edge_k, launched later)
        {
            const float2* g2 = (const float2*)Wg;
            const float2* v2p = (const float2*)Wv;
            unsigned int* go = (unsigned int*)Wgb;
            unsigned int* vo = (unsigned int*)Wvb;
            for (int j = atid; j < 4096; j += asz) {
                float2 a = g2[j], c = v2p[j];
                go[j] = pkbf(a.x, a.y); vo[j] = pkbf(c.x, c.y);
            }
        }
        // embWgT: [j][32], slot k = emb[k]@Wg (k=1..31), slot 0 = emb[32]@Wg
        for (int j = atid; j < 8192; j += asz) {
            int jr = j >> 5, k = j & 31;
            int kk = k ? k : 32;
            float sacc = 0.f;
            if (kk < BOND) {
                int h = jr >> 5, f = jr & 31;
                const float4* er = (const float4*)(emb + (size_t)kk * WID + h * 32);
                const float4* wr = (const float4*)(Wg + h * 1024 + f * 32);
#pragma unroll
                for (int d = 0; d < 8; d++) {
                    float4 e4 = er[d], w4 = wr[d];
                    sacc += e4.x * w4.x + e4.y * w4.y + e4.z * w4.z + e4.w * w4.w;
                }
            }
            embWgT[jr * 32 + k] = f2b(sacc);
        }
        return;
    }

    int n0 = b * 32;
#pragma unroll
    for (int ch = 0; ch < 8; ch++) {
        int flat = ch * 1024 + t * 4;
        int row = flat >> 8, col = flat & 255;
        int n = n0 + row;
        float4 v = (n < N) ? *(const float4*)&x[(size_t)n * WID + col]
                           : make_float4(0.f, 0.f, 0.f, 0.f);
        *(uint2*)&ab[row * 264 + col] = make_uint2(pkbf(v.x, v.y), pkbf(v.z, v.w));
    }
    __syncthreads();
    int w = t >> 6, lane = t & 63, m = lane & 15, kg = lane >> 4;
    // fused passes: acc[pass][mt][nt]; shared A-fragments, interleaved MFMA chains
    v4f acc[2][2][4];
#pragma unroll
    for (int p = 0; p < 2; p++)
#pragma unroll
        for (int mt = 0; mt < 2; mt++)
#pragma unroll
            for (int nt = 0; nt < 4; nt++) acc[p][mt][nt] = (v4f){0.f, 0.f, 0.f, 0.f};
#pragma unroll
    for (int kt = 0; kt < 8; kt++) {
        int k0 = kt * 32 + kg * 8;
        v8bf a0 = *(const v8bf*)&ab[m * 264 + k0];
        v8bf a1 = *(const v8bf*)&ab[(16 + m) * 264 + k0];
#pragma unroll
        for (int nt = 0; nt < 4; nt++) {
            int j = w * 64 + nt * 16 + m;
            v8bf bs = *(const v8bf*)&Wsb[j * 256 + k0];
            v8bf bt = *(const v8bf*)&Wtb[j * 256 + k0];
            // swapped: M-dim = weight rows j, N-dim = nodes
            acc[0][0][nt] = __builtin_amdgcn_mfma_f32_16x16x32_bf16(bs, a0, acc[0][0][nt], 0, 0, 0);
            acc[0][1][nt] = __builtin_amdgcn_mfma_f32_16x16x32_bf16(bs, a1, acc[0][1][nt], 0, 0, 0);
            acc[1][0][nt] = __builtin_amdgcn_mfma_f32_16x16x32_bf16(bt, a0, acc[1][0][nt], 0, 0, 0);
            acc[1][1][nt] = __builtin_amdgcn_mfma_f32_16x16x32_bf16(bt, a1, acc[1][1][nt], 0, 0, 0);
        }
    }
#pragma unroll
    for (int p = 0; p < 2; p++) {
        unsigned short* outp = p ? xtb : xsb;
#pragma unroll
        for (int mt = 0; mt < 2; mt++) {
            int n = n0 + mt * 16 + m;
            if (n < N) {
#pragma unroll
                for (int nt = 0; nt < 4; nt++) {
                    int j0 = w * 64 + nt * 16 + kg * 4;
                    *(uint2*)&outp[(size_t)n * WID + j0] =
                        make_uint2(pkbf(acc[p][mt][nt][0], acc[p][mt][nt][1]),
                                   pkbf(acc[p][mt][nt][2], acc[p][mt][nt][3]));
                }
            }
        }
    }
}

// ============ fused edge pipeline: R4/R6/R7/R9/R11-verified byte-identical ============
__global__ __launch_bounds__(256, 8)
void edge_k(const unsigned short* __restrict__ xsb, const unsigned short* __restrict__ xtb,
            const int* __restrict__ ssrc, const int* __restrict__ stgt,
            const int* __restrict__ sattr, const unsigned short* __restrict__ Wgb,
            const unsigned short* __restrict__ Wvb, const unsigned short* __restrict__ embWgT,
            float* __restrict__ aggact, int E, int NT, int PER) {
    __shared__ unsigned short xxb[8704];      // xn (32 x 264) -> act_t (256 x stride 34)
    __shared__ unsigned short Mld[32 * 40];   // M rows: 32 cols used (bond32 -> slot 0)
    __shared__ int src_s[32], tgt_s[32];
    __shared__ int segmask_s;

    // XCD-aware swizzle
    int tile = (blockIdx.x & 7) * PER + (blockIdx.x >> 3);
    if (tile >= NT) return;
    int t = threadIdx.x;
    int e0 = tile * 32;
    int ne = min(32, E - e0);

    // init: coalesced sorted-payload loads, M rows, segment flush bitmask
    {
        int tgtv = -1;
        if (t < 32) {
            int e = e0 + t;
            src_s[t] = ssrc[e];
            int tg = stgt[e];
            tgt_s[t] = tg;
            int pa = sattr[e];
            uint4* Mr = (uint4*)&Mld[t * 40];
#pragma unroll
            for (int q = 0; q < 4; q++) Mr[q] = make_uint4(0u, 0u, 0u, 0u);
            int a0 = pa & 63, a1 = (pa >> 6) & 63, a2 = (pa >> 12) & 63;
            int c = (a0 != 0) + (a1 != 0) + (a2 != 0);
            float inv = (c > 0) ? 1.f / (float)c : 0.f;
            float wa = inv * (float)(1 + (a1 == a0) + (a2 == a0));
            float wb = inv * (float)(1 + (a2 == a1));
            if (a0) Mld[t * 40 + (a0 & 31)] = f2b(wa);
            if (a1 && a1 != a0) Mld[t * 40 + (a1 & 31)] = f2b(wb);
            if (a2 && a2 != a0 && a2 != a1) Mld[t * 40 + (a2 & 31)] = f2b(inv);
            tgtv = (t < ne) ? tg : -1;
        }
        if (t < 64) {
            int nxt = __shfl_down(tgtv, 1);
            bool flag = (t < ne) && ((t == ne - 1) || (nxt != tgtv));
            unsigned long long bal = __ballot(flag);
            if (t == 0) segmask_s = (int)(unsigned int)bal;
        }
    }
    __syncthreads();

    // P1: gather + GN stats (4-lane butterfly) -> bf16 xn; packed-f32 via asm
    {
        int e = t >> 3, c = t & 7;
        int sn = src_s[e], g = tgt_s[e];
        const uint4* ps = (const uint4*)(xsb + (size_t)sn * WID);
        const uint4* pt = (const uint4*)(xtb + (size_t)g * WID);
        uint4 us[4], ut[4];
#pragma unroll
        for (int i = 0; i < 4; i++) { us[i] = ps[c + 8 * i]; ut[i] = pt[c + 8 * i]; }
        v2f v2[4][4];
        float sum[4], sq[4];
#pragma unroll
        for (int i = 0; i < 4; i++) {
            const unsigned int* au = (const unsigned int*)&us[i];
            const unsigned int* bu = (const unsigned int*)&ut[i];
            v2f s2 = (v2f){0.f, 0.f}, q2 = (v2f){0.f, 0.f};
#pragma unroll
            for (int q = 0; q < 4; q++) {
                v2f a = pk_add(unpk(au[q]), unpk(bu[q]));
                v2[i][q] = a;
                s2 = pk_add(s2, a);
                q2 = pk_fma(a, a, q2);
            }
            sum[i] = s2.x + s2.y;
            sq[i]  = q2.x + q2.y;
        }
#pragma unroll
        for (int mask = 1; mask <= 2; mask <<= 1)
#pragma unroll
            for (int i = 0; i < 4; i++) {
                sum[i] += __shfl_xor(sum[i], mask);
                sq[i]  += __shfl_xor(sq[i], mask);
            }
#pragma unroll
        for (int i = 0; i < 4; i++) {
            float mu = sum[i] * (1.f / 32.f);
            float var = sq[i] * (1.f / 32.f) - mu * mu;
            float rs = rsqrtf(var + EPS_GN);
            float nmr = -mu * rs;
            v2f rs2 = (v2f){rs, rs}, nm2 = (v2f){nmr, nmr};
            unsigned int pk[4];
#pragma unroll
            for (int q = 0; q < 4; q++) {
                v2f r = pk_fma(v2[i][q], rs2, nm2);
                pk[q] = pkbf(r.x, r.y);
            }
            *(uint4*)&xxb[e * 264 + (c + 8 * i) * 8] = make_uint4(pk[0], pk[1], pk[2], pk[3]);
        }
    }
    __syncthreads();

    // P5: gate/val MFMA (single K=32 bias MFMA) -> act stored TRANSPOSED (stride 34)
    {
        int w = t >> 6, lane = t & 63, m = lane & 15, kg = lane >> 4;
        v8bf axn[2][2], aM[2];
#pragma unroll
        for (int mt = 0; mt < 2; mt++) {
            int row = mt * 16 + m;
            axn[0][mt] = *(const v8bf*)&xxb[row * 264 + (w * 2 + 0) * 32 + kg * 8];
            axn[1][mt] = *(const v8bf*)&xxb[row * 264 + (w * 2 + 1) * 32 + kg * 8];
            aM[mt] = *(const v8bf*)&Mld[row * 40 + kg * 8];
        }
        __syncthreads();  // xn fully consumed before act_t overwrites xxb
        v4f z = {0.f, 0.f, 0.f, 0.f};
#pragma unroll
        for (int hh = 0; hh < 2; hh++) {
            int h = w * 2 + hh;
#pragma unroll
            for (int nt = 0; nt < 2; nt++) {
                int fj = nt * 16 + m;
                int j = h * 32 + fj;
                v8bf bWg = *(const v8bf*)&Wgb[h * 1024 + fj * 32 + kg * 8];
                v8bf bWv = *(const v8bf*)&Wvb[h * 1024 + fj * 32 + kg * 8];
                v8bf bE  = *(const v8bf*)&embWgT[j * 32 + kg * 8];
#pragma unroll
                for (int mt = 0; mt < 2; mt++) {
                    v4f cgm = __builtin_amdgcn_mfma_f32_16x16x32_bf16(axn[hh][mt], bWg, z, 0, 0, 0);
                    cgm = __builtin_amdgcn_mfma_f32_16x16x32_bf16(aM[mt], bE, cgm, 0, 0, 0);
                    v4f cv = __builtin_amdgcn_mfma_f32_16x16x32_bf16(axn[hh][mt], bWv, z, 0, 0, 0);
                    v2f g0 = (v2f){fmaxf(cgm[0], 0.f), fmaxf(cgm[1], 0.f)};
                    v2f g1 = (v2f){fmaxf(cgm[2], 0.f), fmaxf(cgm[3], 0.f)};
                    g0 = pk_mul(g0, (v2f){cv[0], cv[1]});
                    g1 = pk_mul(g1, (v2f){cv[2], cv[3]});
                    int e0i = mt * 16 + kg * 4;  // even -> uint-aligned
                    *(unsigned int*)&xxb[j * 34 + e0i]     = pkbf(g0.x, g0.y);
                    *(unsigned int*)&xxb[j * 34 + e0i + 2] = pkbf(g1.x, g1.y);
                }
            }
        }
    }
    __syncthreads();

    // P6: segmented column reduce; packed pair-sums, scalar bit-test flushes
    {
        unsigned int mask = (unsigned int)__builtin_amdgcn_readfirstlane(segmask_s);
        float sum = 0.f;
#pragma unroll
        for (int i = 0; i < 16; i++) {
            unsigned int r = *(const unsigned int*)&xxb[t * 34 + 2 * i];
            if (!((mask >> (2 * i)) & 1)) {
                sum = pairsum(r, sum);
                if ((mask >> (2 * i + 1)) & 1) {
                    int tg = __builtin_amdgcn_readfirstlane(tgt_s[2 * i + 1]);
                    atomicAdd(&aggact[(size_t)tg * WID + t], sum);
                    sum = 0.f;
                }
            } else {
                sum += lo16(r);
                int tg = __builtin_amdgcn_readfirstlane(tgt_s[2 * i]);
                atomicAdd(&aggact[(size_t)tg * WID + t], sum);
                sum = hi16(r);
                if ((mask >> (2 * i + 1)) & 1) {
                    int tg2 = __builtin_amdgcn_readfirstlane(tgt_s[2 * i + 1]);
                    atomicAdd(&aggact[(size_t)tg2 * WID + t], sum);
                    sum = 0.f;
                }
            }
        }
    }
}

// ============ post (R2/R9-verified 32-node tiles, launch_bounds(256,2)) ============
__global__ __launch_bounds__(256, 2)
void post_k(const float* __restrict__ aggact, const unsigned short* __restrict__ Wpb,
            const float* __restrict__ deg, const float* __restrict__ dp,
            float* __restrict__ out, int N) {
    __shared__ unsigned short ab[32 * 264];
    __shared__ float degl[32];
    int t = threadIdx.x;
    int n0 = blockIdx.x * 32;
#pragma unroll
    for (int ch = 0; ch < 8; ch++) {
        int flat = ch * 1024 + t * 4;
        int row = flat >> 8, col = flat & 255;
        int n = n0 + row;
        float4 v = (n < N) ? *(const float4*)&aggact[(size_t)n * WID + col]
                           : make_float4(0.f, 0.f, 0.f, 0.f);
        *(uint2*)&ab[row * 264 + col] = make_uint2(pkbf(v.x, v.y), pkbf(v.z, v.w));
    }
    if (t < 32) {
        int n = n0 + t;
        degl[t] = (n < N) ? log2f(deg[n]) : 0.f;
    }
    __syncthreads();
    int w = t >> 6, lane = t & 63, m = lane & 15, kg = lane >> 4;
    v4f acc[2][4];
#pragma unroll
    for (int mt = 0; mt < 2; mt++)
#pragma unroll
        for (int nt = 0; nt < 4; nt++) acc[mt][nt] = (v4f){0.f, 0.f, 0.f, 0.f};
#pragma unroll
    for (int kt = 0; kt < 8; kt++) {
        int k0 = kt * 32 + kg * 8;
        v8bf a0 = *(const v8bf*)&ab[m * 264 + k0];
        v8bf a1 = *(const v8bf*)&ab[(16 + m) * 264 + k0];
#pragma unroll
        for (int nt = 0; nt < 4; nt++) {
            int j = w * 64 + nt * 16 + m;
            v8bf b = *(const v8bf*)&Wpb[j * 256 + k0];
            // swapped: M-dim = Wp rows j, N-dim = nodes
            acc[0][nt] = __builtin_amdgcn_mfma_f32_16x16x32_bf16(b, a0, acc[0][nt], 0, 0, 0);
            acc[1][nt] = __builtin_amdgcn_mfma_f32_16x16x32_bf16(b, a1, acc[1][nt], 0, 0, 0);
        }
    }
#pragma unroll
    for (int mt = 0; mt < 2; mt++) {
        int n = n0 + mt * 16 + m;
        if (n < N) {
            float ld = degl[mt * 16 + m];
#pragma unroll
            for (int nt = 0; nt < 4; nt++) {
                int j0 = w * 64 + nt * 16 + kg * 4;
                float4 dv = *(const float4*)&dp[j0];
                float4 o;
                o.x = exp2f(dv.x * ld) * acc[mt][nt][0];
                o.y = exp2f(dv.y * ld) * acc[mt][nt][1];
                o.z = exp2f(dv.z * ld) * acc[mt][nt][2];
                o.w = exp2f(dv.w * ld) * acc[mt][nt][3];
                *(float4*)&out[(size_t)n * WID + j0] = o;
            }
        }
    }
}

extern "C" void kernel_launch(void* const* d_in, const int* in_sizes, int n_in,
                              void* d_out, int out_size, void* d_ws, size_t ws_size,
                              hipStream_t stream) {
    const float* x    = (const float*)d_in[0];
    const float* deg  = (const float*)d_in[1];
    const int*   eidx = (const int*)d_in[2];
    const int*   eatt = (const int*)d_in[3];
    const float* Wsrc = (const float*)d_in[4];
    const float* Wtgt = (const float*)d_in[5];
    const float* emb  = (const float*)d_in[6];
    const float* Wg   = (const float*)d_in[7];
    const float* Wv   = (const float*)d_in[8];
    const float* Wp   = (const float*)d_in[9];
    const float* dp   = (const float*)d_in[10];
    int N = in_sizes[0] / WID;
    int E = in_sizes[2] / 2;
    int BOND = in_sizes[6] / WID;

    int NT = (E + 31) / 32;
    int NT32 = NT * 32;

    float* ws     = (float*)d_ws;
    float* aggact = ws;
    int*   cnt    = (int*)(aggact + (size_t)N * WID);
    int*   cur    = cnt + N;
    int*   ssrc   = cur + N;
    int*   stgt   = ssrc + NT32;
    int*   sattr  = stgt + NT32;
    unsigned short* xsb = (unsigned short*)(sattr + NT32);
    unsigned short* xtb = xsb + (size_t)N * WID;
    unsigned short* Wsb = xtb + (size_t)N * WID;
    unsigned short* Wtb = Wsb + 65536;
    unsigned short* Wpb = Wtb + 65536;
    unsigned short* Wgb = Wpb + 65536;
    unsigned short* Wvb = Wgb + 8192;
    unsigned short* embWgT = Wvb + 8192;

    int PB = (N + 31) / 32;
    int AUX = 128;
    int PER = (NT + 7) / 8;

    // ONE memset covers aggact (N*WID floats) + cnt (N ints) — adjacent in ws
    hipMemsetAsync(aggact, 0, (size_t)N * WID * sizeof(float) + (size_t)N * sizeof(int),
                   stream);

    cast_k<<<320, 256, 0, stream>>>(Wsrc, Wtgt, eidx, Wsb, Wtb,
                                    cnt, ssrc, stgt, sattr, N, E, NT32);
    scan_k<<<1, 1024, 0, stream>>>(cnt, cur, N);
    prepproj_k<<<PB + AUX, 256, 0, stream>>>(x, Wsb, Wtb, eidx, eatt, cur,
                                             ssrc, stgt, sattr, xsb, xtb,
                                             Wp, Wg, Wv, emb,
                                             Wpb, Wgb, Wvb, embWgT,
                                             N, E, PB, AUX, BOND);
    edge_k<<<PER * 8, 256, 0, stream>>>(xsb, xtb, ssrc, stgt, sattr, Wgb, Wvb, embWgT,
                                        aggact, E, NT, PER);
    post_k<<<PB, 256, 0, stream>>>(aggact, Wpb, deg, dp, (float*)d_out, N);
}

// Round 14
// 209.110 us; speedup vs baseline: 1.0232x; 1.0097x over previous
//
#include <hip/hip_runtime.h>

#define WID 256
#define EPS_GN 1e-5f

typedef __bf16 v8bf __attribute__((ext_vector_type(8)));
typedef __bf16 v2bf __attribute__((ext_vector_type(2)));
typedef float  v4f  __attribute__((ext_vector_type(4)));
typedef float  v2f  __attribute__((ext_vector_type(2)));

__device__ inline unsigned short f2b(float f) {
    unsigned int u = __builtin_bit_cast(unsigned int, f);
    unsigned int r = (u + 0x7fffu + ((u >> 16) & 1u)) >> 16;
    return (unsigned short)r;
}
__device__ inline float lo16(unsigned int u) { return __builtin_bit_cast(float, u << 16); }
__device__ inline float hi16(unsigned int u) { return __builtin_bit_cast(float, u & 0xffff0000u); }
__device__ inline v2f unpk(unsigned int u) {
    v2f r; r.x = lo16(u); r.y = hi16(u); return r;
}

// ---- real packed-f32 VOP3P (clang scalarizes v2f arithmetic; asm forces pk ops) ----
__device__ inline v2f pk_add(v2f a, v2f b) {
    v2f d; asm("v_pk_add_f32 %0, %1, %2" : "=v"(d) : "v"(a), "v"(b)); return d;
}
__device__ inline v2f pk_mul(v2f a, v2f b) {
    v2f d; asm("v_pk_mul_f32 %0, %1, %2" : "=v"(d) : "v"(a), "v"(b)); return d;
}
__device__ inline v2f pk_fma(v2f a, v2f b, v2f c) {
    v2f d; asm("v_pk_fma_f32 %0, %1, %2, %3" : "=v"(d) : "v"(a), "v"(b), "v"(c)); return d;
}

#if __has_builtin(__builtin_amdgcn_cvt_pk_bf16_f32)
__device__ inline unsigned int pkbf(float a, float b) {
    v2bf r = __builtin_amdgcn_cvt_pk_bf16_f32(a, b);
    return __builtin_bit_cast(unsigned int, r);
}
#else
__device__ inline unsigned int pkbf(float a, float b) {
    return (unsigned int)f2b(a) | ((unsigned int)f2b(b) << 16);
}
#endif

#if __has_builtin(__builtin_amdgcn_fdot2_f32_bf16)
__device__ inline float pairsum(unsigned int u, float s) {
    v2bf p = __builtin_bit_cast(v2bf, u);
    v2bf ones = __builtin_bit_cast(v2bf, 0x3f803f80u);
    return __builtin_amdgcn_fdot2_f32_bf16(p, ones, s, false);
}
#else
__device__ inline float pairsum(unsigned int u, float s) {
    return s + lo16(u) + hi16(u);
}
#endif

// ===== cast (Wsrc/Wtgt) + histogram only — pad-tail moved to prepproj aux =====
// NOTE (R8 lesson): NO __threadfence() — device-scope fence on gfx950 = L2 flush.
__global__ void cast_k(const float* __restrict__ Wsrc, const float* __restrict__ Wtgt,
                       const int* __restrict__ eidx,
                       unsigned short* __restrict__ Wsb, unsigned short* __restrict__ Wtb,
                       int* __restrict__ cnt, int E) {
    int i = blockIdx.x * 256 + threadIdx.x;  // 320*256 = 81920 threads
    int gsz = gridDim.x * 256;
    for (int j = i; j < E; j += gsz) atomicAdd(&cnt[eidx[E + j]], 1);
    {
        const float2* s2 = (const float2*)Wsrc;
        const float2* t2 = (const float2*)Wtgt;
        unsigned int* so = (unsigned int*)Wsb;
        unsigned int* to = (unsigned int*)Wtb;
        for (int j = i; j < 32768; j += gsz) {
            float2 a = s2[j], b = t2[j];
            so[j] = pkbf(a.x, a.y); to[j] = pkbf(b.x, b.y);
        }
    }
}

// ===== exclusive scan: wave-shfl based (R11-verified) =====
__global__ void scan_k(const int* __restrict__ cnt, int* __restrict__ cur, int N) {
    __shared__ int buf[10240];   // N <= 10240
    __shared__ int wsum[16];
    int t = threadIdx.x;         // 1024 threads = 16 waves
    int C = (N + 1023) >> 10;
    int M = C << 10;
    for (int i = t; i < M; i += 1024) buf[i] = (i < N) ? cnt[i] : 0;
    __syncthreads();
    int base0 = t * C;
    int s = 0;
    for (int i = 0; i < C; i++) s += buf[base0 + i];
    int lane = t & 63, wv = t >> 6;
    int v = s;
#pragma unroll
    for (int d = 1; d < 64; d <<= 1) {
        int u = __shfl_up(v, d);
        if (lane >= d) v += u;
    }
    if (lane == 63) wsum[wv] = v;
    __syncthreads();
    if (wv == 0 && lane < 16) {
        int x = wsum[lane];
#pragma unroll
        for (int d = 1; d < 16; d <<= 1) {
            int u = __shfl_up(x, d, 16);
            if (lane >= d) x += u;
        }
        wsum[lane] = x;
    }
    __syncthreads();
    int waveoff = (wv == 0) ? 0 : wsum[wv - 1];
    int base = waveoff + (v - s);
    for (int i = 0; i < C; i++) {
        int val = buf[base0 + i];
        buf[base0 + i] = base;
        base += val;
    }
    __syncthreads();
    for (int i = t; i < N; i += 1024) cur[i] = buf[i];
}

// ===== proj: FUSED two-pass MFMA (R13-verified); aux blocks run SCATTER +
//       aggact zero + pad-tail + remaining weight casts (all overlapped) =====
__global__ __launch_bounds__(256, 2)
void prepproj_k(const float* __restrict__ x, const unsigned short* __restrict__ Wsb,
                const unsigned short* __restrict__ Wtb, const int* __restrict__ eidx,
                const int* __restrict__ eattr, int* __restrict__ cur,
                int* __restrict__ ssrc, int* __restrict__ stgt, int* __restrict__ sattr,
                unsigned short* __restrict__ xsb, unsigned short* __restrict__ xtb,
                const float* __restrict__ Wp, const float* __restrict__ Wg,
                const float* __restrict__ Wv, const float* __restrict__ emb,
                unsigned short* __restrict__ Wpb, unsigned short* __restrict__ Wgb,
                unsigned short* __restrict__ Wvb, unsigned short* __restrict__ embWgT,
                float* __restrict__ aggact,
                int N, int E, int PB, int AUX, int BOND, int NT32) {
    __shared__ unsigned short ab[32 * 264];
    int t = threadIdx.x, b = blockIdx.x;

    if (b >= PB) {
        int atid = (b - PB) * 256 + t, asz = AUX * 256;
        // aggact zero (consumed by edge_k, next kernel — kernel boundary orders it)
        {
            float4* ap = (float4*)aggact;
            int n4 = (N * WID) >> 2;
            for (int i = atid; i < n4; i += asz) ap[i] = make_float4(0.f, 0.f, 0.f, 0.f);
        }
        // pad sorted-edge tail
        for (int j = E + atid; j < NT32; j += asz) { ssrc[j] = 0; stgt[j] = 0; sattr[j] = 0; }
        // scatter: write edge payload directly in sorted position
        for (int i = atid; i < E; i += asz) {
            int tg = eidx[E + i];
            int p = atomicAdd(&cur[tg], 1);
            ssrc[p] = eidx[i];
            stgt[p] = tg;
            const int* ap = eattr + (size_t)i * 3;
            sattr[p] = (ap[0] & 63) | ((ap[1] & 63) << 6) | ((ap[2] & 63) << 12);
        }
        // cast Wp -> Wpb (needed by post_k)
        {
            const float2* p2 = (const float2*)Wp;
            unsigned int* po = (unsigned int*)Wpb;
            for (int j = atid; j < 32768; j += asz) {
                float2 c = p2[j];
                po[j] = pkbf(c.x, c.y);
            }
        }
        // cast Wg/Wv -> Wgb/Wvb (needed by edge_k)
        {
            const float2* g2 = (const float2*)Wg;
            const float2* v2p = (const float2*)Wv;
            unsigned int* go = (unsigned int*)Wgb;
            unsigned int* vo = (unsigned int*)Wvb;
            for (int j = atid; j < 4096; j += asz) {
                float2 a = g2[j], c = v2p[j];
                go[j] = pkbf(a.x, a.y); vo[j] = pkbf(c.x, c.y);
            }
        }
        // embWgT: [j][32], slot k = emb[k]@Wg (k=1..31), slot 0 = emb[32]@Wg
        for (int j = atid; j < 8192; j += asz) {
            int jr = j >> 5, k = j & 31;
            int kk = k ? k : 32;
            float sacc = 0.f;
            if (kk < BOND) {
                int h = jr >> 5, f = jr & 31;
                const float4* er = (const float4*)(emb + (size_t)kk * WID + h * 32);
                const float4* wr = (const float4*)(Wg + h * 1024 + f * 32);
#pragma unroll
                for (int d = 0; d < 8; d++) {
                    float4 e4 = er[d], w4 = wr[d];
                    sacc += e4.x * w4.x + e4.y * w4.y + e4.z * w4.z + e4.w * w4.w;
                }
            }
            embWgT[jr * 32 + k] = f2b(sacc);
        }
        return;
    }

    int n0 = b * 32;
#pragma unroll
    for (int ch = 0; ch < 8; ch++) {
        int flat = ch * 1024 + t * 4;
        int row = flat >> 8, col = flat & 255;
        int n = n0 + row;
        float4 v = (n < N) ? *(const float4*)&x[(size_t)n * WID + col]
                           : make_float4(0.f, 0.f, 0.f, 0.f);
        *(uint2*)&ab[row * 264 + col] = make_uint2(pkbf(v.x, v.y), pkbf(v.z, v.w));
    }
    __syncthreads();
    int w = t >> 6, lane = t & 63, m = lane & 15, kg = lane >> 4;
    // fused passes: acc[pass][mt][nt]; shared A-fragments, interleaved MFMA chains
    v4f acc[2][2][4];
#pragma unroll
    for (int p = 0; p < 2; p++)
#pragma unroll
        for (int mt = 0; mt < 2; mt++)
#pragma unroll
            for (int nt = 0; nt < 4; nt++) acc[p][mt][nt] = (v4f){0.f, 0.f, 0.f, 0.f};
#pragma unroll
    for (int kt = 0; kt < 8; kt++) {
        int k0 = kt * 32 + kg * 8;
        v8bf a0 = *(const v8bf*)&ab[m * 264 + k0];
        v8bf a1 = *(const v8bf*)&ab[(16 + m) * 264 + k0];
#pragma unroll
        for (int nt = 0; nt < 4; nt++) {
            int j = w * 64 + nt * 16 + m;
            v8bf bs = *(const v8bf*)&Wsb[j * 256 + k0];
            v8bf bt = *(const v8bf*)&Wtb[j * 256 + k0];
            // swapped: M-dim = weight rows j, N-dim = nodes
            acc[0][0][nt] = __builtin_amdgcn_mfma_f32_16x16x32_bf16(bs, a0, acc[0][0][nt], 0, 0, 0);
            acc[0][1][nt] = __builtin_amdgcn_mfma_f32_16x16x32_bf16(bs, a1, acc[0][1][nt], 0, 0, 0);
            acc[1][0][nt] = __builtin_amdgcn_mfma_f32_16x16x32_bf16(bt, a0, acc[1][0][nt], 0, 0, 0);
            acc[1][1][nt] = __builtin_amdgcn_mfma_f32_16x16x32_bf16(bt, a1, acc[1][1][nt], 0, 0, 0);
        }
    }
#pragma unroll
    for (int p = 0; p < 2; p++) {
        unsigned short* outp = p ? xtb : xsb;
#pragma unroll
        for (int mt = 0; mt < 2; mt++) {
            int n = n0 + mt * 16 + m;
            if (n < N) {
#pragma unroll
                for (int nt = 0; nt < 4; nt++) {
                    int j0 = w * 64 + nt * 16 + kg * 4;
                    *(uint2*)&outp[(size_t)n * WID + j0] =
                        make_uint2(pkbf(acc[p][mt][nt][0], acc[p][mt][nt][1]),
                                   pkbf(acc[p][mt][nt][2], acc[p][mt][nt][3]));
                }
            }
        }
    }
}

// ============ fused edge pipeline: R4/R6/R7/R9/R11/R13-verified byte-identical ============
__global__ __launch_bounds__(256, 8)
void edge_k(const unsigned short* __restrict__ xsb, const unsigned short* __restrict__ xtb,
            const int* __restrict__ ssrc, const int* __restrict__ stgt,
            const int* __restrict__ sattr, const unsigned short* __restrict__ Wgb,
            const unsigned short* __restrict__ Wvb, const unsigned short* __restrict__ embWgT,
            float* __restrict__ aggact, int E, int NT, int PER) {
    __shared__ unsigned short xxb[8704];      // xn (32 x 264) -> act_t (256 x stride 34)
    __shared__ unsigned short Mld[32 * 40];   // M rows: 32 cols used (bond32 -> slot 0)
    __shared__ int src_s[32], tgt_s[32];
    __shared__ int segmask_s;

    // XCD-aware swizzle
    int tile = (blockIdx.x & 7) * PER + (blockIdx.x >> 3);
    if (tile >= NT) return;
    int t = threadIdx.x;
    int e0 = tile * 32;
    int ne = min(32, E - e0);

    // init: coalesced sorted-payload loads, M rows, segment flush bitmask
    {
        int tgtv = -1;
        if (t < 32) {
            int e = e0 + t;
            src_s[t] = ssrc[e];
            int tg = stgt[e];
            tgt_s[t] = tg;
            int pa = sattr[e];
            uint4* Mr = (uint4*)&Mld[t * 40];
#pragma unroll
            for (int q = 0; q < 4; q++) Mr[q] = make_uint4(0u, 0u, 0u, 0u);
            int a0 = pa & 63, a1 = (pa >> 6) & 63, a2 = (pa >> 12) & 63;
            int c = (a0 != 0) + (a1 != 0) + (a2 != 0);
            float inv = (c > 0) ? 1.f / (float)c : 0.f;
            float wa = inv * (float)(1 + (a1 == a0) + (a2 == a0));
            float wb = inv * (float)(1 + (a2 == a1));
            if (a0) Mld[t * 40 + (a0 & 31)] = f2b(wa);
            if (a1 && a1 != a0) Mld[t * 40 + (a1 & 31)] = f2b(wb);
            if (a2 && a2 != a0 && a2 != a1) Mld[t * 40 + (a2 & 31)] = f2b(inv);
            tgtv = (t < ne) ? tg : -1;
        }
        if (t < 64) {
            int nxt = __shfl_down(tgtv, 1);
            bool flag = (t < ne) && ((t == ne - 1) || (nxt != tgtv));
            unsigned long long bal = __ballot(flag);
            if (t == 0) segmask_s = (int)(unsigned int)bal;
        }
    }
    __syncthreads();

    // P1: gather + GN stats (4-lane butterfly) -> bf16 xn; packed-f32 via asm
    {
        int e = t >> 3, c = t & 7;
        int sn = src_s[e], g = tgt_s[e];
        const uint4* ps = (const uint4*)(xsb + (size_t)sn * WID);
        const uint4* pt = (const uint4*)(xtb + (size_t)g * WID);
        uint4 us[4], ut[4];
#pragma unroll
        for (int i = 0; i < 4; i++) { us[i] = ps[c + 8 * i]; ut[i] = pt[c + 8 * i]; }
        v2f v2[4][4];
        float sum[4], sq[4];
#pragma unroll
        for (int i = 0; i < 4; i++) {
            const unsigned int* au = (const unsigned int*)&us[i];
            const unsigned int* bu = (const unsigned int*)&ut[i];
            v2f s2 = (v2f){0.f, 0.f}, q2 = (v2f){0.f, 0.f};
#pragma unroll
            for (int q = 0; q < 4; q++) {
                v2f a = pk_add(unpk(au[q]), unpk(bu[q]));
                v2[i][q] = a;
                s2 = pk_add(s2, a);
                q2 = pk_fma(a, a, q2);
            }
            sum[i] = s2.x + s2.y;
            sq[i]  = q2.x + q2.y;
        }
#pragma unroll
        for (int mask = 1; mask <= 2; mask <<= 1)
#pragma unroll
            for (int i = 0; i < 4; i++) {
                sum[i] += __shfl_xor(sum[i], mask);
                sq[i]  += __shfl_xor(sq[i], mask);
            }
#pragma unroll
        for (int i = 0; i < 4; i++) {
            float mu = sum[i] * (1.f / 32.f);
            float var = sq[i] * (1.f / 32.f) - mu * mu;
            float rs = rsqrtf(var + EPS_GN);
            float nmr = -mu * rs;
            v2f rs2 = (v2f){rs, rs}, nm2 = (v2f){nmr, nmr};
            unsigned int pk[4];
#pragma unroll
            for (int q = 0; q < 4; q++) {
                v2f r = pk_fma(v2[i][q], rs2, nm2);
                pk[q] = pkbf(r.x, r.y);
            }
            *(uint4*)&xxb[e * 264 + (c + 8 * i) * 8] = make_uint4(pk[0], pk[1], pk[2], pk[3]);
        }
    }
    __syncthreads();

    // P5: gate/val MFMA (single K=32 bias MFMA) -> act stored TRANSPOSED (stride 34)
    {
        int w = t >> 6, lane = t & 63, m = lane & 15, kg = lane >> 4;
        v8bf axn[2][2], aM[2];
#pragma unroll
        for (int mt = 0; mt < 2; mt++) {
            int row = mt * 16 + m;
            axn[0][mt] = *(const v8bf*)&xxb[row * 264 + (w * 2 + 0) * 32 + kg * 8];
            axn[1][mt] = *(const v8bf*)&xxb[row * 264 + (w * 2 + 1) * 32 + kg * 8];
            aM[mt] = *(const v8bf*)&Mld[row * 40 + kg * 8];
        }
        __syncthreads();  // xn fully consumed before act_t overwrites xxb
        v4f z = {0.f, 0.f, 0.f, 0.f};
#pragma unroll
        for (int hh = 0; hh < 2; hh++) {
            int h = w * 2 + hh;
#pragma unroll
            for (int nt = 0; nt < 2; nt++) {
                int fj = nt * 16 + m;
                int j = h * 32 + fj;
                v8bf bWg = *(const v8bf*)&Wgb[h * 1024 + fj * 32 + kg * 8];
                v8bf bWv = *(const v8bf*)&Wvb[h * 1024 + fj * 32 + kg * 8];
                v8bf bE  = *(const v8bf*)&embWgT[j * 32 + kg * 8];
#pragma unroll
                for (int mt = 0; mt < 2; mt++) {
                    v4f cgm = __builtin_amdgcn_mfma_f32_16x16x32_bf16(axn[hh][mt], bWg, z, 0, 0, 0);
                    cgm = __builtin_amdgcn_mfma_f32_16x16x32_bf16(aM[mt], bE, cgm, 0, 0, 0);
                    v4f cv = __builtin_amdgcn_mfma_f32_16x16x32_bf16(axn[hh][mt], bWv, z, 0, 0, 0);
                    v2f g0 = (v2f){fmaxf(cgm[0], 0.f), fmaxf(cgm[1], 0.f)};
                    v2f g1 = (v2f){fmaxf(cgm[2], 0.f), fmaxf(cgm[3], 0.f)};
                    g0 = pk_mul(g0, (v2f){cv[0], cv[1]});
                    g1 = pk_mul(g1, (v2f){cv[2], cv[3]});
                    int e0i = mt * 16 + kg * 4;  // even -> uint-aligned
                    *(unsigned int*)&xxb[j * 34 + e0i]     = pkbf(g0.x, g0.y);
                    *(unsigned int*)&xxb[j * 34 + e0i + 2] = pkbf(g1.x, g1.y);
                }
            }
        }
    }
    __syncthreads();

    // P6: segmented column reduce; packed pair-sums, scalar bit-test flushes
    {
        unsigned int mask = (unsigned int)__builtin_amdgcn_readfirstlane(segmask_s);
        float sum = 0.f;
#pragma unroll
        for (int i = 0; i < 16; i++) {
            unsigned int r = *(const unsigned int*)&xxb[t * 34 + 2 * i];
            if (!((mask >> (2 * i)) & 1)) {
                sum = pairsum(r, sum);
                if ((mask >> (2 * i + 1)) & 1) {
                    int tg = __builtin_amdgcn_readfirstlane(tgt_s[2 * i + 1]);
                    atomicAdd(&aggact[(size_t)tg * WID + t], sum);
                    sum = 0.f;
                }
            } else {
                sum += lo16(r);
                int tg = __builtin_amdgcn_readfirstlane(tgt_s[2 * i]);
                atomicAdd(&aggact[(size_t)tg * WID + t], sum);
                sum = hi16(r);
                if ((mask >> (2 * i + 1)) & 1) {
                    int tg2 = __builtin_amdgcn_readfirstlane(tgt_s[2 * i + 1]);
                    atomicAdd(&aggact[(size_t)tg2 * WID + t], sum);
                    sum = 0.f;
                }
            }
        }
    }
}

// ============ post (R2/R9-verified 32-node tiles, launch_bounds(256,2)) ============
__global__ __launch_bounds__(256, 2)
void post_k(const float* __restrict__ aggact, const unsigned short* __restrict__ Wpb,
            const float* __restrict__ deg, const float* __restrict__ dp,
            float* __restrict__ out, int N) {
    __shared__ unsigned short ab[32 * 264];
    __shared__ float degl[32];
    int t = threadIdx.x;
    int n0 = blockIdx.x * 32;
#pragma unroll
    for (int ch = 0; ch < 8; ch++) {
        int flat = ch * 1024 + t * 4;
        int row = flat >> 8, col = flat & 255;
        int n = n0 + row;
        float4 v = (n < N) ? *(const float4*)&aggact[(size_t)n * WID + col]
                           : make_float4(0.f, 0.f, 0.f, 0.f);
        *(uint2*)&ab[row * 264 + col] = make_uint2(pkbf(v.x, v.y), pkbf(v.z, v.w));
    }
    if (t < 32) {
        int n = n0 + t;
        degl[t] = (n < N) ? log2f(deg[n]) : 0.f;
    }
    __syncthreads();
    int w = t >> 6, lane = t & 63, m = lane & 15, kg = lane >> 4;
    v4f acc[2][4];
#pragma unroll
    for (int mt = 0; mt < 2; mt++)
#pragma unroll
        for (int nt = 0; nt < 4; nt++) acc[mt][nt] = (v4f){0.f, 0.f, 0.f, 0.f};
#pragma unroll
    for (int kt = 0; kt < 8; kt++) {
        int k0 = kt * 32 + kg * 8;
        v8bf a0 = *(const v8bf*)&ab[m * 264 + k0];
        v8bf a1 = *(const v8bf*)&ab[(16 + m) * 264 + k0];
#pragma unroll
        for (int nt = 0; nt < 4; nt++) {
            int j = w * 64 + nt * 16 + m;
            v8bf b = *(const v8bf*)&Wpb[j * 256 + k0];
            // swapped: M-dim = Wp rows j, N-dim = nodes
            acc[0][nt] = __builtin_amdgcn_mfma_f32_16x16x32_bf16(b, a0, acc[0][nt], 0, 0, 0);
            acc[1][nt] = __builtin_amdgcn_mfma_f32_16x16x32_bf16(b, a1, acc[1][nt], 0, 0, 0);
        }
    }
#pragma unroll
    for (int mt = 0; mt < 2; mt++) {
        int n = n0 + mt * 16 + m;
        if (n < N) {
            float ld = degl[mt * 16 + m];
#pragma unroll
            for (int nt = 0; nt < 4; nt++) {
                int j0 = w * 64 + nt * 16 + kg * 4;
                float4 dv = *(const float4*)&dp[j0];
                float4 o;
                o.x = exp2f(dv.x * ld) * acc[mt][nt][0];
                o.y = exp2f(dv.y * ld) * acc[mt][nt][1];
                o.z = exp2f(dv.z * ld) * acc[mt][nt][2];
                o.w = exp2f(dv.w * ld) * acc[mt][nt][3];
                *(float4*)&out[(size_t)n * WID + j0] = o;
            }
        }
    }
}

extern "C" void kernel_launch(void* const* d_in, const int* in_sizes, int n_in,
                              void* d_out, int out_size, void* d_ws, size_t ws_size,
                              hipStream_t stream) {
    const float* x    = (const float*)d_in[0];
    const float* deg  = (const float*)d_in[1];
    const int*   eidx = (const int*)d_in[2];
    const int*   eatt = (const int*)d_in[3];
    const float* Wsrc = (const float*)d_in[4];
    const float* Wtgt = (const float*)d_in[5];
    const float* emb  = (const float*)d_in[6];
    const float* Wg   = (const float*)d_in[7];
    const float* Wv   = (const float*)d_in[8];
    const float* Wp   = (const float*)d_in[9];
    const float* dp   = (const float*)d_in[10];
    int N = in_sizes[0] / WID;
    int E = in_sizes[2] / 2;
    int BOND = in_sizes[6] / WID;

    int NT = (E + 31) / 32;
    int NT32 = NT * 32;

    float* ws     = (float*)d_ws;
    float* aggact = ws;
    int*   cnt    = (int*)(aggact + (size_t)N * WID);
    int*   cur    = cnt + N;
    int*   ssrc   = cur + N;
    int*   stgt   = ssrc + NT32;
    int*   sattr  = stgt + NT32;
    unsigned short* xsb = (unsigned short*)(sattr + NT32);
    unsigned short* xtb = xsb + (size_t)N * WID;
    unsigned short* Wsb = xtb + (size_t)N * WID;
    unsigned short* Wtb = Wsb + 65536;
    unsigned short* Wpb = Wtb + 65536;
    unsigned short* Wgb = Wpb + 65536;
    unsigned short* Wvb = Wgb + 8192;
    unsigned short* embWgT = Wvb + 8192;

    int PB = (N + 31) / 32;
    int AUX = 128;
    int PER = (NT + 7) / 8;

    // tiny memset: only cnt (histogram needs pre-zeroed counts in a prior node)
    hipMemsetAsync(cnt, 0, (size_t)N * sizeof(int), stream);

    cast_k<<<320, 256, 0, stream>>>(Wsrc, Wtgt, eidx, Wsb, Wtb, cnt, E);
    scan_k<<<1, 1024, 0, stream>>>(cnt, cur, N);
    prepproj_k<<<PB + AUX, 256, 0, stream>>>(x, Wsb, Wtb, eidx, eatt, cur,
                                             ssrc, stgt, sattr, xsb, xtb,
                                             Wp, Wg, Wv, emb,
                                             Wpb, Wgb, Wvb, embWgT, aggact,
                                             N, E, PB, AUX, BOND, NT32);
    edge_k<<<PER * 8, 256, 0, stream>>>(xsb, xtb, ssrc, stgt, sattr, Wgb, Wvb, embWgT,
                                        aggact, E, NT, PER);
    post_k<<<PB, 256, 0, stream>>>(aggact, Wpb, deg, dp, (float*)d_out, N);
}

// Round 16
// 207.384 us; speedup vs baseline: 1.0317x; 1.0083x over previous
//
#include <hip/hip_runtime.h>

#define WID 256
#define EPS_GN 1e-5f

typedef __bf16 v8bf __attribute__((ext_vector_type(8)));
typedef __bf16 v2bf __attribute__((ext_vector_type(2)));
typedef float  v4f  __attribute__((ext_vector_type(4)));
typedef float  v2f  __attribute__((ext_vector_type(2)));

__device__ inline unsigned short f2b(float f) {
    unsigned int u = __builtin_bit_cast(unsigned int, f);
    unsigned int r = (u + 0x7fffu + ((u >> 16) & 1u)) >> 16;
    return (unsigned short)r;
}
__device__ inline float lo16(unsigned int u) { return __builtin_bit_cast(float, u << 16); }
__device__ inline float hi16(unsigned int u) { return __builtin_bit_cast(float, u & 0xffff0000u); }
__device__ inline v2f unpk(unsigned int u) {
    v2f r; r.x = lo16(u); r.y = hi16(u); return r;
}

// ---- real packed-f32 VOP3P (clang scalarizes v2f arithmetic; asm forces pk ops) ----
__device__ inline v2f pk_add(v2f a, v2f b) {
    v2f d; asm("v_pk_add_f32 %0, %1, %2" : "=v"(d) : "v"(a), "v"(b)); return d;
}
__device__ inline v2f pk_mul(v2f a, v2f b) {
    v2f d; asm("v_pk_mul_f32 %0, %1, %2" : "=v"(d) : "v"(a), "v"(b)); return d;
}
__device__ inline v2f pk_fma(v2f a, v2f b, v2f c) {
    v2f d; asm("v_pk_fma_f32 %0, %1, %2, %3" : "=v"(d) : "v"(a), "v"(b), "v"(c)); return d;
}

#if __has_builtin(__builtin_amdgcn_cvt_pk_bf16_f32)
__device__ inline unsigned int pkbf(float a, float b) {
    v2bf r = __builtin_amdgcn_cvt_pk_bf16_f32(a, b);
    return __builtin_bit_cast(unsigned int, r);
}
#else
__device__ inline unsigned int pkbf(float a, float b) {
    return (unsigned int)f2b(a) | ((unsigned int)f2b(b) << 16);
}
#endif

#if __has_builtin(__builtin_amdgcn_fdot2_f32_bf16)
__device__ inline float pairsum(unsigned int u, float s) {
    v2bf p = __builtin_bit_cast(v2bf, u);
    v2bf ones = __builtin_bit_cast(v2bf, 0x3f803f80u);
    return __builtin_amdgcn_fdot2_f32_bf16(p, ones, s, false);
}
#else
__device__ inline float pairsum(unsigned int u, float s) {
    return s + lo16(u) + hi16(u);
}
#endif

// ===== cast (Wsrc/Wtgt) + histogram only (R14-verified) =====
// NOTE (R8 lesson): NO __threadfence() — device-scope fence on gfx950 = L2 flush.
__global__ void cast_k(const float* __restrict__ Wsrc, const float* __restrict__ Wtgt,
                       const int* __restrict__ eidx,
                       unsigned short* __restrict__ Wsb, unsigned short* __restrict__ Wtb,
                       int* __restrict__ cnt, int E) {
    int i = blockIdx.x * 256 + threadIdx.x;  // 320*256 = 81920 threads
    int gsz = gridDim.x * 256;
    for (int j = i; j < E; j += gsz) atomicAdd(&cnt[eidx[E + j]], 1);
    {
        const float2* s2 = (const float2*)Wsrc;
        const float2* t2 = (const float2*)Wtgt;
        unsigned int* so = (unsigned int*)Wsb;
        unsigned int* to = (unsigned int*)Wtb;
        for (int j = i; j < 32768; j += gsz) {
            float2 a = s2[j], b = t2[j];
            so[j] = pkbf(a.x, a.y); to[j] = pkbf(b.x, b.y);
        }
    }
}

// ===== exclusive scan: wave-shfl based (R11-verified) =====
__global__ void scan_k(const int* __restrict__ cnt, int* __restrict__ cur, int N) {
    __shared__ int buf[10240];   // N <= 10240
    __shared__ int wsum[16];
    int t = threadIdx.x;         // 1024 threads = 16 waves
    int C = (N + 1023) >> 10;
    int M = C << 10;
    for (int i = t; i < M; i += 1024) buf[i] = (i < N) ? cnt[i] : 0;
    __syncthreads();
    int base0 = t * C;
    int s = 0;
    for (int i = 0; i < C; i++) s += buf[base0 + i];
    int lane = t & 63, wv = t >> 6;
    int v = s;
#pragma unroll
    for (int d = 1; d < 64; d <<= 1) {
        int u = __shfl_up(v, d);
        if (lane >= d) v += u;
    }
    if (lane == 63) wsum[wv] = v;
    __syncthreads();
    if (wv == 0 && lane < 16) {
        int x = wsum[lane];
#pragma unroll
        for (int d = 1; d < 16; d <<= 1) {
            int u = __shfl_up(x, d, 16);
            if (lane >= d) x += u;
        }
        wsum[lane] = x;
    }
    __syncthreads();
    int waveoff = (wv == 0) ? 0 : wsum[wv - 1];
    int base = waveoff + (v - s);
    for (int i = 0; i < C; i++) {
        int val = buf[base0 + i];
        buf[base0 + i] = base;
        base += val;
    }
    __syncthreads();
    for (int i = t; i < N; i += 1024) cur[i] = buf[i];
}

// ===== proj: FUSED two-pass MFMA; aux blocks run SCATTER + zeros + casts (R14) =====
__global__ __launch_bounds__(256, 2)
void prepproj_k(const float* __restrict__ x, const unsigned short* __restrict__ Wsb,
                const unsigned short* __restrict__ Wtb, const int* __restrict__ eidx,
                const int* __restrict__ eattr, int* __restrict__ cur,
                int* __restrict__ ssrc, int* __restrict__ stgt, int* __restrict__ sattr,
                unsigned short* __restrict__ xsb, unsigned short* __restrict__ xtb,
                const float* __restrict__ Wp, const float* __restrict__ Wg,
                const float* __restrict__ Wv, const float* __restrict__ emb,
                unsigned short* __restrict__ Wpb, unsigned short* __restrict__ Wgb,
                unsigned short* __restrict__ Wvb, unsigned short* __restrict__ embWgT,
                float* __restrict__ aggact,
                int N, int E, int PB, int AUX, int BOND, int NT32) {
    __shared__ unsigned short ab[32 * 264];
    int t = threadIdx.x, b = blockIdx.x;

    if (b >= PB) {
        int atid = (b - PB) * 256 + t, asz = AUX * 256;
        // aggact zero (consumed by edge_k — kernel boundary orders it)
        {
            float4* ap = (float4*)aggact;
            int n4 = (N * WID) >> 2;
            for (int i = atid; i < n4; i += asz) ap[i] = make_float4(0.f, 0.f, 0.f, 0.f);
        }
        // pad sorted-edge tail
        for (int j = E + atid; j < NT32; j += asz) { ssrc[j] = 0; stgt[j] = 0; sattr[j] = 0; }
        // scatter: write edge payload directly in sorted position
        for (int i = atid; i < E; i += asz) {
            int tg = eidx[E + i];
            int p = atomicAdd(&cur[tg], 1);
            ssrc[p] = eidx[i];
            stgt[p] = tg;
            const int* ap = eattr + (size_t)i * 3;
            sattr[p] = (ap[0] & 63) | ((ap[1] & 63) << 6) | ((ap[2] & 63) << 12);
        }
        // cast Wp -> Wpb (needed by post_k)
        {
            const float2* p2 = (const float2*)Wp;
            unsigned int* po = (unsigned int*)Wpb;
            for (int j = atid; j < 32768; j += asz) {
                float2 c = p2[j];
                po[j] = pkbf(c.x, c.y);
            }
        }
        // cast Wg/Wv -> Wgb/Wvb (needed by edge_k)
        {
            const float2* g2 = (const float2*)Wg;
            const float2* v2p = (const float2*)Wv;
            unsigned int* go = (unsigned int*)Wgb;
            unsigned int* vo = (unsigned int*)Wvb;
            for (int j = atid; j < 4096; j += asz) {
                float2 a = g2[j], c = v2p[j];
                go[j] = pkbf(a.x, a.y); vo[j] = pkbf(c.x, c.y);
            }
        }
        // embWgT: [j][32], slot k = emb[k]@Wg (k=1..31), slot 0 = emb[32]@Wg
        for (int j = atid; j < 8192; j += asz) {
            int jr = j >> 5, k = j & 31;
            int kk = k ? k : 32;
            float sacc = 0.f;
            if (kk < BOND) {
                int h = jr >> 5, f = jr & 31;
                const float4* er = (const float4*)(emb + (size_t)kk * WID + h * 32);
                const float4* wr = (const float4*)(Wg + h * 1024 + f * 32);
#pragma unroll
                for (int d = 0; d < 8; d++) {
                    float4 e4 = er[d], w4 = wr[d];
                    sacc += e4.x * w4.x + e4.y * w4.y + e4.z * w4.z + e4.w * w4.w;
                }
            }
            embWgT[jr * 32 + k] = f2b(sacc);
        }
        return;
    }

    int n0 = b * 32;
#pragma unroll
    for (int ch = 0; ch < 8; ch++) {
        int flat = ch * 1024 + t * 4;
        int row = flat >> 8, col = flat & 255;
        int n = n0 + row;
        float4 v = (n < N) ? *(const float4*)&x[(size_t)n * WID + col]
                           : make_float4(0.f, 0.f, 0.f, 0.f);
        *(uint2*)&ab[row * 264 + col] = make_uint2(pkbf(v.x, v.y), pkbf(v.z, v.w));
    }
    __syncthreads();
    int w = t >> 6, lane = t & 63, m = lane & 15, kg = lane >> 4;
    v4f acc[2][2][4];
#pragma unroll
    for (int p = 0; p < 2; p++)
#pragma unroll
        for (int mt = 0; mt < 2; mt++)
#pragma unroll
            for (int nt = 0; nt < 4; nt++) acc[p][mt][nt] = (v4f){0.f, 0.f, 0.f, 0.f};
#pragma unroll
    for (int kt = 0; kt < 8; kt++) {
        int k0 = kt * 32 + kg * 8;
        v8bf a0 = *(const v8bf*)&ab[m * 264 + k0];
        v8bf a1 = *(const v8bf*)&ab[(16 + m) * 264 + k0];
#pragma unroll
        for (int nt = 0; nt < 4; nt++) {
            int j = w * 64 + nt * 16 + m;
            v8bf bs = *(const v8bf*)&Wsb[j * 256 + k0];
            v8bf bt = *(const v8bf*)&Wtb[j * 256 + k0];
            // swapped: M-dim = weight rows j, N-dim = nodes
            acc[0][0][nt] = __builtin_amdgcn_mfma_f32_16x16x32_bf16(bs, a0, acc[0][0][nt], 0, 0, 0);
            acc[0][1][nt] = __builtin_amdgcn_mfma_f32_16x16x32_bf16(bs, a1, acc[0][1][nt], 0, 0, 0);
            acc[1][0][nt] = __builtin_amdgcn_mfma_f32_16x16x32_bf16(bt, a0, acc[1][0][nt], 0, 0, 0);
            acc[1][1][nt] = __builtin_amdgcn_mfma_f32_16x16x32_bf16(bt, a1, acc[1][1][nt], 0, 0, 0);
        }
    }
#pragma unroll
    for (int p = 0; p < 2; p++) {
        unsigned short* outp = p ? xtb : xsb;
#pragma unroll
        for (int mt = 0; mt < 2; mt++) {
            int n = n0 + mt * 16 + m;
            if (n < N) {
#pragma unroll
                for (int nt = 0; nt < 4; nt++) {
                    int j0 = w * 64 + nt * 16 + kg * 4;
                    *(uint2*)&outp[(size_t)n * WID + j0] =
                        make_uint2(pkbf(acc[p][mt][nt][0], acc[p][mt][nt][1]),
                                   pkbf(acc[p][mt][nt][2], acc[p][mt][nt][3]));
                }
            }
        }
    }
}

// ============ fused edge pipeline: R14-verified byte-identical (structure FROZEN) ============
__global__ __launch_bounds__(256, 8)
void edge_k(const unsigned short* __restrict__ xsb, const unsigned short* __restrict__ xtb,
            const int* __restrict__ ssrc, const int* __restrict__ stgt,
            const int* __restrict__ sattr, const unsigned short* __restrict__ Wgb,
            const unsigned short* __restrict__ Wvb, const unsigned short* __restrict__ embWgT,
            float* __restrict__ aggact, int E, int NT, int PER) {
    __shared__ unsigned short xxb[8704];      // xn (32 x 264) -> act_t (256 x stride 34)
    __shared__ unsigned short Mld[32 * 40];   // M rows: 32 cols used (bond32 -> slot 0)
    __shared__ int src_s[32], tgt_s[32];
    __shared__ int segmask_s;

    // XCD-aware swizzle
    int tile = (blockIdx.x & 7) * PER + (blockIdx.x >> 3);
    if (tile >= NT) return;
    int t = threadIdx.x;
    int e0 = tile * 32;
    int ne = min(32, E - e0);

    // init: coalesced sorted-payload loads, M rows, segment flush bitmask
    {
        int tgtv = -1;
        if (t < 32) {
            int e = e0 + t;
            src_s[t] = ssrc[e];
            int tg = stgt[e];
            tgt_s[t] = tg;
            int pa = sattr[e];
            uint4* Mr = (uint4*)&Mld[t * 40];
#pragma unroll
            for (int q = 0; q < 4; q++) Mr[q] = make_uint4(0u, 0u, 0u, 0u);
            int a0 = pa & 63, a1 = (pa >> 6) & 63, a2 = (pa >> 12) & 63;
            int c = (a0 != 0) + (a1 != 0) + (a2 != 0);
            float inv = (c > 0) ? 1.f / (float)c : 0.f;
            float wa = inv * (float)(1 + (a1 == a0) + (a2 == a0));
            float wb = inv * (float)(1 + (a2 == a1));
            if (a0) Mld[t * 40 + (a0 & 31)] = f2b(wa);
            if (a1 && a1 != a0) Mld[t * 40 + (a1 & 31)] = f2b(wb);
            if (a2 && a2 != a0 && a2 != a1) Mld[t * 40 + (a2 & 31)] = f2b(inv);
            tgtv = (t < ne) ? tg : -1;
        }
        if (t < 64) {
            int nxt = __shfl_down(tgtv, 1);
            bool flag = (t < ne) && ((t == ne - 1) || (nxt != tgtv));
            unsigned long long bal = __ballot(flag);
            if (t == 0) segmask_s = (int)(unsigned int)bal;
        }
    }
    __syncthreads();

    // P1: gather + GN stats (4-lane butterfly) -> bf16 xn; packed-f32 via asm
    {
        int e = t >> 3, c = t & 7;
        int sn = src_s[e], g = tgt_s[e];
        const uint4* ps = (const uint4*)(xsb + (size_t)sn * WID);
        const uint4* pt = (const uint4*)(xtb + (size_t)g * WID);
        uint4 us[4], ut[4];
#pragma unroll
        for (int i = 0; i < 4; i++) { us[i] = ps[c + 8 * i]; ut[i] = pt[c + 8 * i]; }
        v2f v2[4][4];
        float sum[4], sq[4];
#pragma unroll
        for (int i = 0; i < 4; i++) {
            const unsigned int* au = (const unsigned int*)&us[i];
            const unsigned int* bu = (const unsigned int*)&ut[i];
            v2f s2 = (v2f){0.f, 0.f}, q2 = (v2f){0.f, 0.f};
#pragma unroll
            for (int q = 0; q < 4; q++) {
                v2f a = pk_add(unpk(au[q]), unpk(bu[q]));
                v2[i][q] = a;
                s2 = pk_add(s2, a);
                q2 = pk_fma(a, a, q2);
            }
            sum[i] = s2.x + s2.y;
            sq[i]  = q2.x + q2.y;
        }
#pragma unroll
        for (int mask = 1; mask <= 2; mask <<= 1)
#pragma unroll
            for (int i = 0; i < 4; i++) {
                sum[i] += __shfl_xor(sum[i], mask);
                sq[i]  += __shfl_xor(sq[i], mask);
            }
#pragma unroll
        for (int i = 0; i < 4; i++) {
            float mu = sum[i] * (1.f / 32.f);
            float var = sq[i] * (1.f / 32.f) - mu * mu;
            float rs = rsqrtf(var + EPS_GN);
            float nmr = -mu * rs;
            v2f rs2 = (v2f){rs, rs}, nm2 = (v2f){nmr, nmr};
            unsigned int pk[4];
#pragma unroll
            for (int q = 0; q < 4; q++) {
                v2f r = pk_fma(v2[i][q], rs2, nm2);
                pk[q] = pkbf(r.x, r.y);
            }
            *(uint4*)&xxb[e * 264 + (c + 8 * i) * 8] = make_uint4(pk[0], pk[1], pk[2], pk[3]);
        }
    }
    __syncthreads();

    // P5: gate/val MFMA (single K=32 bias MFMA) -> act stored TRANSPOSED (stride 34)
    {
        int w = t >> 6, lane = t & 63, m = lane & 15, kg = lane >> 4;
        v8bf axn[2][2], aM[2];
#pragma unroll
        for (int mt = 0; mt < 2; mt++) {
            int row = mt * 16 + m;
            axn[0][mt] = *(const v8bf*)&xxb[row * 264 + (w * 2 + 0) * 32 + kg * 8];
            axn[1][mt] = *(const v8bf*)&xxb[row * 264 + (w * 2 + 1) * 32 + kg * 8];
            aM[mt] = *(const v8bf*)&Mld[row * 40 + kg * 8];
        }
        __syncthreads();  // xn fully consumed before act_t overwrites xxb
        v4f z = {0.f, 0.f, 0.f, 0.f};
#pragma unroll
        for (int hh = 0; hh < 2; hh++) {
            int h = w * 2 + hh;
#pragma unroll
            for (int nt = 0; nt < 2; nt++) {
                int fj = nt * 16 + m;
                int j = h * 32 + fj;
                v8bf bWg = *(const v8bf*)&Wgb[h * 1024 + fj * 32 + kg * 8];
                v8bf bWv = *(const v8bf*)&Wvb[h * 1024 + fj * 32 + kg * 8];
                v8bf bE  = *(const v8bf*)&embWgT[j * 32 + kg * 8];
#pragma unroll
                for (int mt = 0; mt < 2; mt++) {
                    v4f cgm = __builtin_amdgcn_mfma_f32_16x16x32_bf16(axn[hh][mt], bWg, z, 0, 0, 0);
                    cgm = __builtin_amdgcn_mfma_f32_16x16x32_bf16(aM[mt], bE, cgm, 0, 0, 0);
                    v4f cv = __builtin_amdgcn_mfma_f32_16x16x32_bf16(axn[hh][mt], bWv, z, 0, 0, 0);
                    v2f g0 = (v2f){fmaxf(cgm[0], 0.f), fmaxf(cgm[1], 0.f)};
                    v2f g1 = (v2f){fmaxf(cgm[2], 0.f), fmaxf(cgm[3], 0.f)};
                    g0 = pk_mul(g0, (v2f){cv[0], cv[1]});
                    g1 = pk_mul(g1, (v2f){cv[2], cv[3]});
                    int e0i = mt * 16 + kg * 4;  // even -> uint-aligned
                    *(unsigned int*)&xxb[j * 34 + e0i]     = pkbf(g0.x, g0.y);
                    *(unsigned int*)&xxb[j * 34 + e0i + 2] = pkbf(g1.x, g1.y);
                }
            }
        }
    }
    __syncthreads();

    // P6: segmented column reduce; packed pair-sums, scalar bit-test flushes
    {
        unsigned int mask = (unsigned int)__builtin_amdgcn_readfirstlane(segmask_s);
        float sum = 0.f;
#pragma unroll
        for (int i = 0; i < 16; i++) {
            unsigned int r = *(const unsigned int*)&xxb[t * 34 + 2 * i];
            if (!((mask >> (2 * i)) & 1)) {
                sum = pairsum(r, sum);
                if ((mask >> (2 * i + 1)) & 1) {
                    int tg = __builtin_amdgcn_readfirstlane(tgt_s[2 * i + 1]);
                    atomicAdd(&aggact[(size_t)tg * WID + t], sum);
                    sum = 0.f;
                }
            } else {
                sum += lo16(r);
                int tg = __builtin_amdgcn_readfirstlane(tgt_s[2 * i]);
                atomicAdd(&aggact[(size_t)tg * WID + t], sum);
                sum = hi16(r);
                if ((mask >> (2 * i + 1)) & 1) {
                    int tg2 = __builtin_amdgcn_readfirstlane(tgt_s[2 * i + 1]);
                    atomicAdd(&aggact[(size_t)tg2 * WID + t], sum);
                    sum = 0.f;
                }
            }
        }
    }
}

// ============ post (R2/R9-verified 32-node tiles, launch_bounds(256,2)) ============
__global__ __launch_bounds__(256, 2)
void post_k(const float* __restrict__ aggact, const unsigned short* __restrict__ Wpb,
            const float* __restrict__ deg, const float* __restrict__ dp,
            float* __restrict__ out, int N) {
    __shared__ unsigned short ab[32 * 264];
    __shared__ float degl[32];
    int t = threadIdx.x;
    int n0 = blockIdx.x * 32;
#pragma unroll
    for (int ch = 0; ch < 8; ch++) {
        int flat = ch * 1024 + t * 4;
        int row = flat >> 8, col = flat & 255;
        int n = n0 + row;
        float4 v = (n < N) ? *(const float4*)&aggact[(size_t)n * WID + col]
                           : make_float4(0.f, 0.f, 0.f, 0.f);
        *(uint2*)&ab[row * 264 + col] = make_uint2(pkbf(v.x, v.y), pkbf(v.z, v.w));
    }
    if (t < 32) {
        int n = n0 + t;
        degl[t] = (n < N) ? log2f(deg[n]) : 0.f;
    }
    __syncthreads();
    int w = t >> 6, lane = t & 63, m = lane & 15, kg = lane >> 4;
    v4f acc[2][4];
#pragma unroll
    for (int mt = 0; mt < 2; mt++)
#pragma unroll
        for (int nt = 0; nt < 4; nt++) acc[mt][nt] = (v4f){0.f, 0.f, 0.f, 0.f};
#pragma unroll
    for (int kt = 0; kt < 8; kt++) {
        int k0 = kt * 32 + kg * 8;
        v8bf a0 = *(const v8bf*)&ab[m * 264 + k0];
        v8bf a1 = *(const v8bf*)&ab[(16 + m) * 264 + k0];
#pragma unroll
        for (int nt = 0; nt < 4; nt++) {
            int j = w * 64 + nt * 16 + m;
            v8bf b = *(const v8bf*)&Wpb[j * 256 + k0];
            // swapped: M-dim = Wp rows j, N-dim = nodes
            acc[0][nt] = __builtin_amdgcn_mfma_f32_16x16x32_bf16(b, a0, acc[0][nt], 0, 0, 0);
            acc[1][nt] = __builtin_amdgcn_mfma_f32_16x16x32_bf16(b, a1, acc[1][nt], 0, 0, 0);
        }
    }
#pragma unroll
    for (int mt = 0; mt < 2; mt++) {
        int n = n0 + mt * 16 + m;
        if (n < N) {
            float ld = degl[mt * 16 + m];
#pragma unroll
            for (int nt = 0; nt < 4; nt++) {
                int j0 = w * 64 + nt * 16 + kg * 4;
                float4 dv = *(const float4*)&dp[j0];
                float4 o;
                o.x = exp2f(dv.x * ld) * acc[mt][nt][0];
                o.y = exp2f(dv.y * ld) * acc[mt][nt][1];
                o.z = exp2f(dv.z * ld) * acc[mt][nt][2];
                o.w = exp2f(dv.w * ld) * acc[mt][nt][3];
                *(float4*)&out[(size_t)n * WID + j0] = o;
            }
        }
    }
}

extern "C" void kernel_launch(void* const* d_in, const int* in_sizes, int n_in,
                              void* d_out, int out_size, void* d_ws, size_t ws_size,
                              hipStream_t stream) {
    const float* x    = (const float*)d_in[0];
    const float* deg  = (const float*)d_in[1];
    const int*   eidx = (const int*)d_in[2];
    const int*   eatt = (const int*)d_in[3];
    const float* Wsrc = (const float*)d_in[4];
    const float* Wtgt = (const float*)d_in[5];
    const float* emb  = (const float*)d_in[6];
    const float* Wg   = (const float*)d_in[7];
    const float* Wv   = (const float*)d_in[8];
    const float* Wp   = (const float*)d_in[9];
    const float* dp   = (const float*)d_in[10];
    int N = in_sizes[0] / WID;
    int E = in_sizes[2] / 2;
    int BOND = in_sizes[6] / WID;

    int NT = (E + 31) / 32;
    int NT32 = NT * 32;

    float* ws     = (float*)d_ws;
    float* aggact = ws;
    int*   cnt    = (int*)(aggact + (size_t)N * WID);
    int*   cur    = cnt + N;
    int*   ssrc   = cur + N;
    int*   stgt   = ssrc + NT32;
    int*   sattr  = stgt + NT32;
    unsigned short* xsb = (unsigned short*)(sattr + NT32);
    unsigned short* xtb = xsb + (size_t)N * WID;
    unsigned short* Wsb = xtb + (size_t)N * WID;
    unsigned short* Wtb = Wsb + 65536;
    unsigned short* Wpb = Wtb + 65536;
    unsigned short* Wgb = Wpb + 65536;
    unsigned short* Wvb = Wgb + 8192;
    unsigned short* embWgT = Wvb + 8192;

    int PB = (N + 31) / 32;
    int AUX = (PB < 448) ? (512 - PB) : 64;   // fill all 512 co-resident block slots
    int PER = (NT + 7) / 8;

    // tiny memset: only cnt (histogram needs pre-zeroed counts in a prior node)
    hipMemsetAsync(cnt, 0, (size_t)N * sizeof(int), stream);

    cast_k<<<320, 256, 0, stream>>>(Wsrc, Wtgt, eidx, Wsb, Wtb, cnt, E);
    scan_k<<<1, 1024, 0, stream>>>(cnt, cur, N);
    prepproj_k<<<PB + AUX, 256, 0, stream>>>(x, Wsb, Wtb, eidx, eatt, cur,
                                             ssrc, stgt, sattr, xsb, xtb,
                                             Wp, Wg, Wv, emb,
                                             Wpb, Wgb, Wvb, embWgT, aggact,
                                             N, E, PB, AUX, BOND, NT32);
    edge_k<<<PER * 8, 256, 0, stream>>>(xsb, xtb, ssrc, stgt, sattr, Wgb, Wvb, embWgT,
                                        aggact, E, NT, PER);
    post_k<<<PB, 256, 0, stream>>>(aggact, Wpb, deg, dp, (float*)d_out, N);
}

// Round 17
// 206.899 us; speedup vs baseline: 1.0341x; 1.0023x over previous
//
#include <hip/hip_runtime.h>

#define WID 256
#define EPS_GN 1e-5f

typedef __bf16 v8bf __attribute__((ext_vector_type(8)));
typedef __bf16 v2bf __attribute__((ext_vector_type(2)));
typedef float  v4f  __attribute__((ext_vector_type(4)));
typedef float  v2f  __attribute__((ext_vector_type(2)));

__device__ inline unsigned short f2b(float f) {
    unsigned int u = __builtin_bit_cast(unsigned int, f);
    unsigned int r = (u + 0x7fffu + ((u >> 16) & 1u)) >> 16;
    return (unsigned short)r;
}
__device__ inline float lo16(unsigned int u) { return __builtin_bit_cast(float, u << 16); }
__device__ inline float hi16(unsigned int u) { return __builtin_bit_cast(float, u & 0xffff0000u); }
__device__ inline v2f unpk(unsigned int u) {
    v2f r; r.x = lo16(u); r.y = hi16(u); return r;
}

// ---- real packed-f32 VOP3P (clang scalarizes v2f arithmetic; asm forces pk ops) ----
__device__ inline v2f pk_add(v2f a, v2f b) {
    v2f d; asm("v_pk_add_f32 %0, %1, %2" : "=v"(d) : "v"(a), "v"(b)); return d;
}
__device__ inline v2f pk_mul(v2f a, v2f b) {
    v2f d; asm("v_pk_mul_f32 %0, %1, %2" : "=v"(d) : "v"(a), "v"(b)); return d;
}
__device__ inline v2f pk_fma(v2f a, v2f b, v2f c) {
    v2f d; asm("v_pk_fma_f32 %0, %1, %2, %3" : "=v"(d) : "v"(a), "v"(b), "v"(c)); return d;
}

#if __has_builtin(__builtin_amdgcn_cvt_pk_bf16_f32)
__device__ inline unsigned int pkbf(float a, float b) {
    v2bf r = __builtin_amdgcn_cvt_pk_bf16_f32(a, b);
    return __builtin_bit_cast(unsigned int, r);
}
#else
__device__ inline unsigned int pkbf(float a, float b) {
    return (unsigned int)f2b(a) | ((unsigned int)f2b(b) << 16);
}
#endif

#if __has_builtin(__builtin_amdgcn_fdot2_f32_bf16)
__device__ inline float pairsum(unsigned int u, float s) {
    v2bf p = __builtin_bit_cast(v2bf, u);
    v2bf ones = __builtin_bit_cast(v2bf, 0x3f803f80u);
    return __builtin_amdgcn_fdot2_f32_bf16(p, ones, s, false);
}
#else
__device__ inline float pairsum(unsigned int u, float s) {
    return s + lo16(u) + hi16(u);
}
#endif

// ===== cast (Wsrc/Wtgt) + histogram only (R14/R16-verified) =====
// NOTE (R8 lesson): NO __threadfence() — device-scope fence on gfx950 = L2 flush.
__global__ void cast_k(const float* __restrict__ Wsrc, const float* __restrict__ Wtgt,
                       const int* __restrict__ eidx,
                       unsigned short* __restrict__ Wsb, unsigned short* __restrict__ Wtb,
                       int* __restrict__ cnt, int E) {
    int i = blockIdx.x * 256 + threadIdx.x;  // 320*256 = 81920 threads
    int gsz = gridDim.x * 256;
    for (int j = i; j < E; j += gsz) atomicAdd(&cnt[eidx[E + j]], 1);
    {
        const float2* s2 = (const float2*)Wsrc;
        const float2* t2 = (const float2*)Wtgt;
        unsigned int* so = (unsigned int*)Wsb;
        unsigned int* to = (unsigned int*)Wtb;
        for (int j = i; j < 32768; j += gsz) {
            float2 a = s2[j], b = t2[j];
            so[j] = pkbf(a.x, a.y); to[j] = pkbf(b.x, b.y);
        }
    }
}

// ===== exclusive scan: wave-shfl based (R11-verified) =====
__global__ void scan_k(const int* __restrict__ cnt, int* __restrict__ cur, int N) {
    __shared__ int buf[10240];   // N <= 10240
    __shared__ int wsum[16];
    int t = threadIdx.x;         // 1024 threads = 16 waves
    int C = (N + 1023) >> 10;
    int M = C << 10;
    for (int i = t; i < M; i += 1024) buf[i] = (i < N) ? cnt[i] : 0;
    __syncthreads();
    int base0 = t * C;
    int s = 0;
    for (int i = 0; i < C; i++) s += buf[base0 + i];
    int lane = t & 63, wv = t >> 6;
    int v = s;
#pragma unroll
    for (int d = 1; d < 64; d <<= 1) {
        int u = __shfl_up(v, d);
        if (lane >= d) v += u;
    }
    if (lane == 63) wsum[wv] = v;
    __syncthreads();
    if (wv == 0 && lane < 16) {
        int x = wsum[lane];
#pragma unroll
        for (int d = 1; d < 16; d <<= 1) {
            int u = __shfl_up(x, d, 16);
            if (lane >= d) x += u;
        }
        wsum[lane] = x;
    }
    __syncthreads();
    int waveoff = (wv == 0) ? 0 : wsum[wv - 1];
    int base = waveoff + (v - s);
    for (int i = 0; i < C; i++) {
        int val = buf[base0 + i];
        buf[base0 + i] = base;
        base += val;
    }
    __syncthreads();
    for (int i = t; i < N; i += 1024) cur[i] = buf[i];
}

// ===== proj: FUSED two-pass MFMA; aux blocks run SCATTER (int4 payload) +
//       zeros + casts (R16 structure, packed-payload stores) =====
__global__ __launch_bounds__(256, 2)
void prepproj_k(const float* __restrict__ x, const unsigned short* __restrict__ Wsb,
                const unsigned short* __restrict__ Wtb, const int* __restrict__ eidx,
                const int* __restrict__ eattr, int* __restrict__ cur,
                int4* __restrict__ epay,
                unsigned short* __restrict__ xsb, unsigned short* __restrict__ xtb,
                const float* __restrict__ Wp, const float* __restrict__ Wg,
                const float* __restrict__ Wv, const float* __restrict__ emb,
                unsigned short* __restrict__ Wpb, unsigned short* __restrict__ Wgb,
                unsigned short* __restrict__ Wvb, unsigned short* __restrict__ embWgT,
                float* __restrict__ aggact,
                int N, int E, int PB, int AUX, int BOND, int NT32) {
    __shared__ unsigned short ab[32 * 264];
    int t = threadIdx.x, b = blockIdx.x;

    if (b >= PB) {
        int atid = (b - PB) * 256 + t, asz = AUX * 256;
        // aggact zero (consumed by edge_k — kernel boundary orders it)
        {
            float4* ap = (float4*)aggact;
            int n4 = (N * WID) >> 2;
            for (int i = atid; i < n4; i += asz) ap[i] = make_float4(0.f, 0.f, 0.f, 0.f);
        }
        // pad sorted-edge tail (one int4 store)
        for (int j = E + atid; j < NT32; j += asz) epay[j] = make_int4(0, 0, 0, 0);
        // scatter: ONE 16B store per edge (was 3 random 4B stores)
        for (int i = atid; i < E; i += asz) {
            int tg = eidx[E + i];
            int p = atomicAdd(&cur[tg], 1);
            const int* ap = eattr + (size_t)i * 3;
            epay[p] = make_int4(eidx[i], tg,
                                (ap[0] & 63) | ((ap[1] & 63) << 6) | ((ap[2] & 63) << 12), 0);
        }
        // cast Wp -> Wpb (needed by post_k)
        {
            const float2* p2 = (const float2*)Wp;
            unsigned int* po = (unsigned int*)Wpb;
            for (int j = atid; j < 32768; j += asz) {
                float2 c = p2[j];
                po[j] = pkbf(c.x, c.y);
            }
        }
        // cast Wg/Wv -> Wgb/Wvb (needed by edge_k)
        {
            const float2* g2 = (const float2*)Wg;
            const float2* v2p = (const float2*)Wv;
            unsigned int* go = (unsigned int*)Wgb;
            unsigned int* vo = (unsigned int*)Wvb;
            for (int j = atid; j < 4096; j += asz) {
                float2 a = g2[j], c = v2p[j];
                go[j] = pkbf(a.x, a.y); vo[j] = pkbf(c.x, c.y);
            }
        }
        // embWgT: [j][32], slot k = emb[k]@Wg (k=1..31), slot 0 = emb[32]@Wg
        for (int j = atid; j < 8192; j += asz) {
            int jr = j >> 5, k = j & 31;
            int kk = k ? k : 32;
            float sacc = 0.f;
            if (kk < BOND) {
                int h = jr >> 5, f = jr & 31;
                const float4* er = (const float4*)(emb + (size_t)kk * WID + h * 32);
                const float4* wr = (const float4*)(Wg + h * 1024 + f * 32);
#pragma unroll
                for (int d = 0; d < 8; d++) {
                    float4 e4 = er[d], w4 = wr[d];
                    sacc += e4.x * w4.x + e4.y * w4.y + e4.z * w4.z + e4.w * w4.w;
                }
            }
            embWgT[jr * 32 + k] = f2b(sacc);
        }
        return;
    }

    int n0 = b * 32;
#pragma unroll
    for (int ch = 0; ch < 8; ch++) {
        int flat = ch * 1024 + t * 4;
        int row = flat >> 8, col = flat & 255;
        int n = n0 + row;
        float4 v = (n < N) ? *(const float4*)&x[(size_t)n * WID + col]
                           : make_float4(0.f, 0.f, 0.f, 0.f);
        *(uint2*)&ab[row * 264 + col] = make_uint2(pkbf(v.x, v.y), pkbf(v.z, v.w));
    }
    __syncthreads();
    int w = t >> 6, lane = t & 63, m = lane & 15, kg = lane >> 4;
    v4f acc[2][2][4];
#pragma unroll
    for (int p = 0; p < 2; p++)
#pragma unroll
        for (int mt = 0; mt < 2; mt++)
#pragma unroll
            for (int nt = 0; nt < 4; nt++) acc[p][mt][nt] = (v4f){0.f, 0.f, 0.f, 0.f};
#pragma unroll
    for (int kt = 0; kt < 8; kt++) {
        int k0 = kt * 32 + kg * 8;
        v8bf a0 = *(const v8bf*)&ab[m * 264 + k0];
        v8bf a1 = *(const v8bf*)&ab[(16 + m) * 264 + k0];
#pragma unroll
        for (int nt = 0; nt < 4; nt++) {
            int j = w * 64 + nt * 16 + m;
            v8bf bs = *(const v8bf*)&Wsb[j * 256 + k0];
            v8bf bt = *(const v8bf*)&Wtb[j * 256 + k0];
            // swapped: M-dim = weight rows j, N-dim = nodes
            acc[0][0][nt] = __builtin_amdgcn_mfma_f32_16x16x32_bf16(bs, a0, acc[0][0][nt], 0, 0, 0);
            acc[0][1][nt] = __builtin_amdgcn_mfma_f32_16x16x32_bf16(bs, a1, acc[0][1][nt], 0, 0, 0);
            acc[1][0][nt] = __builtin_amdgcn_mfma_f32_16x16x32_bf16(bt, a0, acc[1][0][nt], 0, 0, 0);
            acc[1][1][nt] = __builtin_amdgcn_mfma_f32_16x16x32_bf16(bt, a1, acc[1][1][nt], 0, 0, 0);
        }
    }
#pragma unroll
    for (int p = 0; p < 2; p++) {
        unsigned short* outp = p ? xtb : xsb;
#pragma unroll
        for (int mt = 0; mt < 2; mt++) {
            int n = n0 + mt * 16 + m;
            if (n < N) {
#pragma unroll
                for (int nt = 0; nt < 4; nt++) {
                    int j0 = w * 64 + nt * 16 + kg * 4;
                    *(uint2*)&outp[(size_t)n * WID + j0] =
                        make_uint2(pkbf(acc[p][mt][nt][0], acc[p][mt][nt][1]),
                                   pkbf(acc[p][mt][nt][2], acc[p][mt][nt][3]));
                }
            }
        }
    }
}

// ===== fused edge pipeline: R14/R16 structure; init reads packed int4 payload =====
__global__ __launch_bounds__(256, 8)
void edge_k(const unsigned short* __restrict__ xsb, const unsigned short* __restrict__ xtb,
            const int4* __restrict__ epay, const unsigned short* __restrict__ Wgb,
            const unsigned short* __restrict__ Wvb, const unsigned short* __restrict__ embWgT,
            float* __restrict__ aggact, int E, int NT, int PER) {
    __shared__ unsigned short xxb[8704];      // xn (32 x 264) -> act_t (256 x stride 34)
    __shared__ unsigned short Mld[32 * 40];   // M rows: 32 cols used (bond32 -> slot 0)
    __shared__ int src_s[32], tgt_s[32];
    __shared__ int segmask_s;

    // XCD-aware swizzle
    int tile = (blockIdx.x & 7) * PER + (blockIdx.x >> 3);
    if (tile >= NT) return;
    int t = threadIdx.x;
    int e0 = tile * 32;
    int ne = min(32, E - e0);

    // init: ONE coalesced int4 payload load, M rows, segment flush bitmask
    {
        int tgtv = -1;
        if (t < 32) {
            int4 pv = epay[e0 + t];
            src_s[t] = pv.x;
            int tg = pv.y;
            tgt_s[t] = tg;
            int pa = pv.z;
            uint4* Mr = (uint4*)&Mld[t * 40];
#pragma unroll
            for (int q = 0; q < 4; q++) Mr[q] = make_uint4(0u, 0u, 0u, 0u);
            int a0 = pa & 63, a1 = (pa >> 6) & 63, a2 = (pa >> 12) & 63;
            int c = (a0 != 0) + (a1 != 0) + (a2 != 0);
            float inv = (c > 0) ? 1.f / (float)c : 0.f;
            float wa = inv * (float)(1 + (a1 == a0) + (a2 == a0));
            float wb = inv * (float)(1 + (a2 == a1));
            if (a0) Mld[t * 40 + (a0 & 31)] = f2b(wa);
            if (a1 && a1 != a0) Mld[t * 40 + (a1 & 31)] = f2b(wb);
            if (a2 && a2 != a0 && a2 != a1) Mld[t * 40 + (a2 & 31)] = f2b(inv);
            tgtv = (t < ne) ? tg : -1;
        }
        if (t < 64) {
            int nxt = __shfl_down(tgtv, 1);
            bool flag = (t < ne) && ((t == ne - 1) || (nxt != tgtv));
            unsigned long long bal = __ballot(flag);
            if (t == 0) segmask_s = (int)(unsigned int)bal;
        }
    }
    __syncthreads();

    // P1: gather + GN stats (4-lane butterfly) -> bf16 xn; packed-f32 via asm
    {
        int e = t >> 3, c = t & 7;
        int sn = src_s[e], g = tgt_s[e];
        const uint4* ps = (const uint4*)(xsb + (size_t)sn * WID);
        const uint4* pt = (const uint4*)(xtb + (size_t)g * WID);
        uint4 us[4], ut[4];
#pragma unroll
        for (int i = 0; i < 4; i++) { us[i] = ps[c + 8 * i]; ut[i] = pt[c + 8 * i]; }
        v2f v2[4][4];
        float sum[4], sq[4];
#pragma unroll
        for (int i = 0; i < 4; i++) {
            const unsigned int* au = (const unsigned int*)&us[i];
            const unsigned int* bu = (const unsigned int*)&ut[i];
            v2f s2 = (v2f){0.f, 0.f}, q2 = (v2f){0.f, 0.f};
#pragma unroll
            for (int q = 0; q < 4; q++) {
                v2f a = pk_add(unpk(au[q]), unpk(bu[q]));
                v2[i][q] = a;
                s2 = pk_add(s2, a);
                q2 = pk_fma(a, a, q2);
            }
            sum[i] = s2.x + s2.y;
            sq[i]  = q2.x + q2.y;
        }
#pragma unroll
        for (int mask = 1; mask <= 2; mask <<= 1)
#pragma unroll
            for (int i = 0; i < 4; i++) {
                sum[i] += __shfl_xor(sum[i], mask);
                sq[i]  += __shfl_xor(sq[i], mask);
            }
#pragma unroll
        for (int i = 0; i < 4; i++) {
            float mu = sum[i] * (1.f / 32.f);
            float var = sq[i] * (1.f / 32.f) - mu * mu;
            float rs = rsqrtf(var + EPS_GN);
            float nmr = -mu * rs;
            v2f rs2 = (v2f){rs, rs}, nm2 = (v2f){nmr, nmr};
            unsigned int pk[4];
#pragma unroll
            for (int q = 0; q < 4; q++) {
                v2f r = pk_fma(v2[i][q], rs2, nm2);
                pk[q] = pkbf(r.x, r.y);
            }
            *(uint4*)&xxb[e * 264 + (c + 8 * i) * 8] = make_uint4(pk[0], pk[1], pk[2], pk[3]);
        }
    }
    __syncthreads();

    // P5: gate/val MFMA (single K=32 bias MFMA) -> act stored TRANSPOSED (stride 34)
    {
        int w = t >> 6, lane = t & 63, m = lane & 15, kg = lane >> 4;
        v8bf axn[2][2], aM[2];
#pragma unroll
        for (int mt = 0; mt < 2; mt++) {
            int row = mt * 16 + m;
            axn[0][mt] = *(const v8bf*)&xxb[row * 264 + (w * 2 + 0) * 32 + kg * 8];
            axn[1][mt] = *(const v8bf*)&xxb[row * 264 + (w * 2 + 1) * 32 + kg * 8];
            aM[mt] = *(const v8bf*)&Mld[row * 40 + kg * 8];
        }
        __syncthreads();  // xn fully consumed before act_t overwrites xxb
        v4f z = {0.f, 0.f, 0.f, 0.f};
#pragma unroll
        for (int hh = 0; hh < 2; hh++) {
            int h = w * 2 + hh;
#pragma unroll
            for (int nt = 0; nt < 2; nt++) {
                int fj = nt * 16 + m;
                int j = h * 32 + fj;
                v8bf bWg = *(const v8bf*)&Wgb[h * 1024 + fj * 32 + kg * 8];
                v8bf bWv = *(const v8bf*)&Wvb[h * 1024 + fj * 32 + kg * 8];
                v8bf bE  = *(const v8bf*)&embWgT[j * 32 + kg * 8];
#pragma unroll
                for (int mt = 0; mt < 2; mt++) {
                    v4f cgm = __builtin_amdgcn_mfma_f32_16x16x32_bf16(axn[hh][mt], bWg, z, 0, 0, 0);
                    cgm = __builtin_amdgcn_mfma_f32_16x16x32_bf16(aM[mt], bE, cgm, 0, 0, 0);
                    v4f cv = __builtin_amdgcn_mfma_f32_16x16x32_bf16(axn[hh][mt], bWv, z, 0, 0, 0);
                    v2f g0 = (v2f){fmaxf(cgm[0], 0.f), fmaxf(cgm[1], 0.f)};
                    v2f g1 = (v2f){fmaxf(cgm[2], 0.f), fmaxf(cgm[3], 0.f)};
                    g0 = pk_mul(g0, (v2f){cv[0], cv[1]});
                    g1 = pk_mul(g1, (v2f){cv[2], cv[3]});
                    int e0i = mt * 16 + kg * 4;  // even -> uint-aligned
                    *(unsigned int*)&xxb[j * 34 + e0i]     = pkbf(g0.x, g0.y);
                    *(unsigned int*)&xxb[j * 34 + e0i + 2] = pkbf(g1.x, g1.y);
                }
            }
        }
    }
    __syncthreads();

    // P6: segmented column reduce; packed pair-sums, scalar bit-test flushes
    {
        unsigned int mask = (unsigned int)__builtin_amdgcn_readfirstlane(segmask_s);
        float sum = 0.f;
#pragma unroll
        for (int i = 0; i < 16; i++) {
            unsigned int r = *(const unsigned int*)&xxb[t * 34 + 2 * i];
            if (!((mask >> (2 * i)) & 1)) {
                sum = pairsum(r, sum);
                if ((mask >> (2 * i + 1)) & 1) {
                    int tg = __builtin_amdgcn_readfirstlane(tgt_s[2 * i + 1]);
                    atomicAdd(&aggact[(size_t)tg * WID + t], sum);
                    sum = 0.f;
                }
            } else {
                sum += lo16(r);
                int tg = __builtin_amdgcn_readfirstlane(tgt_s[2 * i]);
                atomicAdd(&aggact[(size_t)tg * WID + t], sum);
                sum = hi16(r);
                if ((mask >> (2 * i + 1)) & 1) {
                    int tg2 = __builtin_amdgcn_readfirstlane(tgt_s[2 * i + 1]);
                    atomicAdd(&aggact[(size_t)tg2 * WID + t], sum);
                    sum = 0.f;
                }
            }
        }
    }
}

// ============ post (R2/R9-verified 32-node tiles, launch_bounds(256,2)) ============
__global__ __launch_bounds__(256, 2)
void post_k(const float* __restrict__ aggact, const unsigned short* __restrict__ Wpb,
            const float* __restrict__ deg, const float* __restrict__ dp,
            float* __restrict__ out, int N) {
    __shared__ unsigned short ab[32 * 264];
    __shared__ float degl[32];
    int t = threadIdx.x;
    int n0 = blockIdx.x * 32;
#pragma unroll
    for (int ch = 0; ch < 8; ch++) {
        int flat = ch * 1024 + t * 4;
        int row = flat >> 8, col = flat & 255;
        int n = n0 + row;
        float4 v = (n < N) ? *(const float4*)&aggact[(size_t)n * WID + col]
                           : make_float4(0.f, 0.f, 0.f, 0.f);
        *(uint2*)&ab[row * 264 + col] = make_uint2(pkbf(v.x, v.y), pkbf(v.z, v.w));
    }
    if (t < 32) {
        int n = n0 + t;
        degl[t] = (n < N) ? log2f(deg[n]) : 0.f;
    }
    __syncthreads();
    int w = t >> 6, lane = t & 63, m = lane & 15, kg = lane >> 4;
    v4f acc[2][4];
#pragma unroll
    for (int mt = 0; mt < 2; mt++)
#pragma unroll
        for (int nt = 0; nt < 4; nt++) acc[mt][nt] = (v4f){0.f, 0.f, 0.f, 0.f};
#pragma unroll
    for (int kt = 0; kt < 8; kt++) {
        int k0 = kt * 32 + kg * 8;
        v8bf a0 = *(const v8bf*)&ab[m * 264 + k0];
        v8bf a1 = *(const v8bf*)&ab[(16 + m) * 264 + k0];
#pragma unroll
        for (int nt = 0; nt < 4; nt++) {
            int j = w * 64 + nt * 16 + m;
            v8bf b = *(const v8bf*)&Wpb[j * 256 + k0];
            // swapped: M-dim = Wp rows j, N-dim = nodes
            acc[0][nt] = __builtin_amdgcn_mfma_f32_16x16x32_bf16(b, a0, acc[0][nt], 0, 0, 0);
            acc[1][nt] = __builtin_amdgcn_mfma_f32_16x16x32_bf16(b, a1, acc[1][nt], 0, 0, 0);
        }
    }
#pragma unroll
    for (int mt = 0; mt < 2; mt++) {
        int n = n0 + mt * 16 + m;
        if (n < N) {
            float ld = degl[mt * 16 + m];
#pragma unroll
            for (int nt = 0; nt < 4; nt++) {
                int j0 = w * 64 + nt * 16 + kg * 4;
                float4 dv = *(const float4*)&dp[j0];
                float4 o;
                o.x = exp2f(dv.x * ld) * acc[mt][nt][0];
                o.y = exp2f(dv.y * ld) * acc[mt][nt][1];
                o.z = exp2f(dv.z * ld) * acc[mt][nt][2];
                o.w = exp2f(dv.w * ld) * acc[mt][nt][3];
                *(float4*)&out[(size_t)n * WID + j0] = o;
            }
        }
    }
}

extern "C" void kernel_launch(void* const* d_in, const int* in_sizes, int n_in,
                              void* d_out, int out_size, void* d_ws, size_t ws_size,
                              hipStream_t stream) {
    const float* x    = (const float*)d_in[0];
    const float* deg  = (const float*)d_in[1];
    const int*   eidx = (const int*)d_in[2];
    const int*   eatt = (const int*)d_in[3];
    const float* Wsrc = (const float*)d_in[4];
    const float* Wtgt = (const float*)d_in[5];
    const float* emb  = (const float*)d_in[6];
    const float* Wg   = (const float*)d_in[7];
    const float* Wv   = (const float*)d_in[8];
    const float* Wp   = (const float*)d_in[9];
    const float* dp   = (const float*)d_in[10];
    int N = in_sizes[0] / WID;
    int E = in_sizes[2] / 2;
    int BOND = in_sizes[6] / WID;

    int NT = (E + 31) / 32;
    int NT32 = NT * 32;

    float* ws     = (float*)d_ws;
    float* aggact = ws;
    int*   cnt    = (int*)(aggact + (size_t)N * WID);
    int*   cur    = cnt + N;
    // pad to 16B alignment for the int4 payload
    size_t payoff = (((size_t)(N * WID) + 2 * N) + 3) & ~(size_t)3;
    int4*  epay   = (int4*)(ws + payoff);
    unsigned short* xsb = (unsigned short*)(epay + NT32);
    unsigned short* xtb = xsb + (size_t)N * WID;
    unsigned short* Wsb = xtb + (size_t)N * WID;
    unsigned short* Wtb = Wsb + 65536;
    unsigned short* Wpb = Wtb + 65536;
    unsigned short* Wgb = Wpb + 65536;
    unsigned short* Wvb = Wgb + 8192;
    unsigned short* embWgT = Wvb + 8192;

    int PB = (N + 31) / 32;
    int AUX = (PB < 448) ? (512 - PB) : 64;   // fill all 512 co-resident block slots
    int PER = (NT + 7) / 8;

    // tiny memset: only cnt (histogram needs pre-zeroed counts in a prior node)
    hipMemsetAsync(cnt, 0, (size_t)N * sizeof(int), stream);

    cast_k<<<320, 256, 0, stream>>>(Wsrc, Wtgt, eidx, Wsb, Wtb, cnt, E);
    scan_k<<<1, 1024, 0, stream>>>(cnt, cur, N);
    prepproj_k<<<PB + AUX, 256, 0, stream>>>(x, Wsb, Wtb, eidx, eatt, cur,
                                             epay, xsb, xtb,
                                             Wp, Wg, Wv, emb,
                                             Wpb, Wgb, Wvb, embWgT, aggact,
                                             N, E, PB, AUX, BOND, NT32);
    edge_k<<<PER * 8, 256, 0, stream>>>(xsb, xtb, epay, Wgb, Wvb, embWgT,
                                        aggact, E, NT, PER);
    post_k<<<PB, 256, 0, stream>>>(aggact, Wpb, deg, dp, (float*)d_out, N);
}